// Round 1
// baseline (1952.232 us; speedup 1.0000x reference)
//
#include <hip/hip_runtime.h>
#include <math.h>

#define N_NODES 10000
#define N_EDGES 320000
#define HIDDEN  128
#define NUM_RBF 20
#define H3      384   // 3*HIDDEN

// ---------------------------------------------------------------------------
// Kernel 1: out[0:NQ) = q ; out[NQ:NQ+NMU) = mu   (f32, float4-vectorized)
// ---------------------------------------------------------------------------
__global__ void copy_init_kernel(const float4* __restrict__ q,
                                 const float4* __restrict__ mu,
                                 float4* __restrict__ out) {
    const int n_q4  = N_NODES * HIDDEN / 4;        // 320000
    const int n_mu4 = N_NODES * 3 * HIDDEN / 4;    // 960000
    const int stride = gridDim.x * blockDim.x;
    const int tid = blockIdx.x * blockDim.x + threadIdx.x;
    for (int i = tid; i < n_q4; i += stride)  out[i] = q[i];
    for (int i = tid; i < n_mu4; i += stride) out[n_q4 + i] = mu[i];
}

// ---------------------------------------------------------------------------
// Kernel 2: node MLP  x = silu(q@W1 + b1) @ W2 + b2    -> ws  [N_NODES][384]
// 32 nodes per block, 384 threads (thread j owns output column j).
// ---------------------------------------------------------------------------
__global__ __launch_bounds__(384) void node_mlp_kernel(
    const float* __restrict__ q,
    const float* __restrict__ W1, const float* __restrict__ b1,
    const float* __restrict__ W2, const float* __restrict__ b2,
    float* __restrict__ x) {

    __shared__ float q_s[32][HIDDEN];   // 16 KB
    __shared__ float h_s[32][H3];       // 48 KB

    const int n0 = blockIdx.x * 32;
    const int nt = min(32, N_NODES - n0);
    const int t  = threadIdx.x;
    const int j  = t;                   // 0..383

    // load q rows (zero-fill past-end rows so math stays finite)
    for (int idx = t; idx < 32 * HIDDEN; idx += 384) {
        const int i = idx >> 7, k = idx & 127;
        q_s[i][k] = (i < nt) ? q[(n0 + i) * HIDDEN + k] : 0.0f;
    }
    __syncthreads();

    // layer 1: hidden[i][j] = silu(b1[j] + sum_k q[i][k]*W1[k][j])
    {
        const float bb = b1[j];
        const float* wp = W1 + j;
        for (int i0 = 0; i0 < 32; i0 += 16) {
            float acc[16];
#pragma unroll
            for (int u = 0; u < 16; ++u) acc[u] = bb;
            for (int k4 = 0; k4 < HIDDEN / 4; ++k4) {
                const float w0 = wp[(4 * k4 + 0) * H3];
                const float w1 = wp[(4 * k4 + 1) * H3];
                const float w2 = wp[(4 * k4 + 2) * H3];
                const float w3 = wp[(4 * k4 + 3) * H3];
#pragma unroll
                for (int u = 0; u < 16; ++u) {
                    const float4 h4 =
                        reinterpret_cast<const float4*>(&q_s[i0 + u][0])[k4];
                    acc[u] = fmaf(h4.x, w0, acc[u]);
                    acc[u] = fmaf(h4.y, w1, acc[u]);
                    acc[u] = fmaf(h4.z, w2, acc[u]);
                    acc[u] = fmaf(h4.w, w3, acc[u]);
                }
            }
#pragma unroll
            for (int u = 0; u < 16; ++u) {
                const float v = acc[u];
                h_s[i0 + u][j] = v / (1.0f + __expf(-v));   // silu
            }
        }
    }
    __syncthreads();

    // layer 2: x[i][j] = b2[j] + sum_k h[i][k]*W2[k][j]
    {
        const float bb = b2[j];
        const float* wp = W2 + j;
        for (int i0 = 0; i0 < 32; i0 += 16) {
            float acc[16];
#pragma unroll
            for (int u = 0; u < 16; ++u) acc[u] = bb;
            for (int k4 = 0; k4 < H3 / 4; ++k4) {
                const float w0 = wp[(4 * k4 + 0) * H3];
                const float w1 = wp[(4 * k4 + 1) * H3];
                const float w2 = wp[(4 * k4 + 2) * H3];
                const float w3 = wp[(4 * k4 + 3) * H3];
#pragma unroll
                for (int u = 0; u < 16; ++u) {
                    const float4 h4 =
                        reinterpret_cast<const float4*>(&h_s[i0 + u][0])[k4];
                    acc[u] = fmaf(h4.x, w0, acc[u]);
                    acc[u] = fmaf(h4.y, w1, acc[u]);
                    acc[u] = fmaf(h4.z, w2, acc[u]);
                    acc[u] = fmaf(h4.w, w3, acc[u]);
                }
            }
#pragma unroll
            for (int u = 0; u < 16; ++u) {
                if (i0 + u < nt) x[(n0 + i0 + u) * H3 + j] = acc[u];
            }
        }
    }
}

// ---------------------------------------------------------------------------
// Kernel 3: per-edge filter MLP + gather-multiply-scatter (atomics into out)
// 32 edges per block, 384 threads, grid = N_EDGES/32 = 10000 blocks.
// ---------------------------------------------------------------------------
__global__ __launch_bounds__(384) void edge_kernel(
    const float* __restrict__ x,          // [N,384] from node MLP
    const float* __restrict__ mu,         // [N,3,128]
    const int*   __restrict__ edge_index, // [2,E]: row0=target, row1=source
    const float* __restrict__ rbf,        // [E,20]
    const float* __restrict__ uv,         // [E,3]
    const float* __restrict__ cut,        // [E]
    const float* __restrict__ Wf1, const float* __restrict__ bf1,
    const float* __restrict__ Wf2, const float* __restrict__ bf2,
    float* __restrict__ out_q,            // [N,128]  (pre-initialized to q)
    float* __restrict__ out_mu) {         // [N,3,128](pre-initialized to mu)

    __shared__ float rbf_s[32][NUM_RBF];  // 2.5 KB
    __shared__ float h1_s[32][HIDDEN];    // 16 KB
    __shared__ float f_s[32][H3];         // 48 KB
    __shared__ int   src_s[32], tgt_s[32];
    __shared__ float uv_s[32][3], cut_s[32];

    const int e0 = blockIdx.x * 32;
    const int t  = threadIdx.x;

    // ---- stage per-edge small data ----
    for (int idx = t; idx < 32 * NUM_RBF; idx += 384) {
        rbf_s[idx / NUM_RBF][idx % NUM_RBF] = rbf[e0 * NUM_RBF + idx];
    }
    if (t < 32) {
        tgt_s[t] = edge_index[e0 + t];            // row 0 = target
        src_s[t] = edge_index[N_EDGES + e0 + t];  // row 1 = source
        cut_s[t] = cut[e0 + t];
    } else if (t < 32 + 96) {
        const int u = t - 32;
        uv_s[u / 3][u % 3] = uv[e0 * 3 + u];
    }
    __syncthreads();

    // ---- filter layer 1: [32,20] @ [20,128] -> silu -> h1_s ----
    {
        const int col = t & 127;
        const int grp = t >> 7;       // 0..2
        const float bb = bf1[col];
        for (int i = grp; i < 32; i += 3) {
            float acc = bb;
#pragma unroll
            for (int k = 0; k < NUM_RBF; ++k)
                acc = fmaf(rbf_s[i][k], Wf1[k * HIDDEN + col], acc);
            h1_s[i][col] = acc / (1.0f + __expf(-acc));
        }
    }
    __syncthreads();

    // ---- filter layer 2: [32,128] @ [128,384] + bf2, * cutoff -> f_s ----
    {
        const int j = t;
        const float bb = bf2[j];
        const float* wp = Wf2 + j;
        for (int i0 = 0; i0 < 32; i0 += 16) {
            float acc[16];
#pragma unroll
            for (int u = 0; u < 16; ++u) acc[u] = bb;
            for (int k4 = 0; k4 < HIDDEN / 4; ++k4) {
                const float w0 = wp[(4 * k4 + 0) * H3];
                const float w1 = wp[(4 * k4 + 1) * H3];
                const float w2 = wp[(4 * k4 + 2) * H3];
                const float w3 = wp[(4 * k4 + 3) * H3];
#pragma unroll
                for (int u = 0; u < 16; ++u) {
                    const float4 h4 =
                        reinterpret_cast<const float4*>(&h1_s[i0 + u][0])[k4];
                    acc[u] = fmaf(h4.x, w0, acc[u]);
                    acc[u] = fmaf(h4.y, w1, acc[u]);
                    acc[u] = fmaf(h4.z, w2, acc[u]);
                    acc[u] = fmaf(h4.w, w3, acc[u]);
                }
            }
#pragma unroll
            for (int u = 0; u < 16; ++u)
                f_s[i0 + u][j] = acc[u] * cut_s[i0 + u];
        }
    }
    __syncthreads();

    // ---- messages: gather x[src], mu[src]; scatter-add into out ----
    {
        const int c   = t & 127;
        const int grp = t >> 7;
        for (int i = grp; i < 32; i += 3) {
            const int src = src_s[i];
            const int tgt = tgt_s[i];
            const float xq = x[src * H3 + c];
            const float xr = x[src * H3 + HIDDEN + c];
            const float xm = x[src * H3 + 2 * HIDDEN + c];
            const float fq = f_s[i][c];
            const float fr = f_s[i][HIDDEN + c];
            const float fm = f_s[i][2 * HIDDEN + c];

            atomicAdd(&out_q[tgt * HIDDEN + c], xq * fq);

            const float xrr = xr * fr;
            const float xmm = xm * fm;
            const float u0 = uv_s[i][0], u1 = uv_s[i][1], u2 = uv_s[i][2];
            atomicAdd(&out_mu[(tgt * 3 + 0) * HIDDEN + c],
                      fmaf(u0, xrr, mu[(src * 3 + 0) * HIDDEN + c] * xmm));
            atomicAdd(&out_mu[(tgt * 3 + 1) * HIDDEN + c],
                      fmaf(u1, xrr, mu[(src * 3 + 1) * HIDDEN + c] * xmm));
            atomicAdd(&out_mu[(tgt * 3 + 2) * HIDDEN + c],
                      fmaf(u2, xrr, mu[(src * 3 + 2) * HIDDEN + c] * xmm));
        }
    }
}

// ---------------------------------------------------------------------------
extern "C" void kernel_launch(void* const* d_in, const int* in_sizes, int n_in,
                              void* d_out, int out_size, void* d_ws, size_t ws_size,
                              hipStream_t stream) {
    const float* q   = (const float*)d_in[0];
    const float* mu  = (const float*)d_in[1];
    const int*   ei  = (const int*)  d_in[2];
    const float* rbf = (const float*)d_in[3];
    const float* uv  = (const float*)d_in[4];
    const float* cut = (const float*)d_in[5];
    const float* W1  = (const float*)d_in[6];
    const float* b1  = (const float*)d_in[7];
    const float* W2  = (const float*)d_in[8];
    const float* b2  = (const float*)d_in[9];
    const float* Wf1 = (const float*)d_in[10];
    const float* bf1 = (const float*)d_in[11];
    const float* Wf2 = (const float*)d_in[12];
    const float* bf2 = (const float*)d_in[13];

    float* out   = (float*)d_out;
    float* out_q = out;                        // [N,128]
    float* out_mu = out + N_NODES * HIDDEN;    // [N,3,128]
    float* x = (float*)d_ws;                   // [N,384] scratch (15.36 MB)

    // 1) out = concat(q, mu)
    copy_init_kernel<<<1280, 256, 0, stream>>>(
        (const float4*)q, (const float4*)mu, (float4*)d_out);

    // 2) node MLP -> x
    node_mlp_kernel<<<(N_NODES + 31) / 32, 384, 0, stream>>>(
        q, W1, b1, W2, b2, x);

    // 3) edge messages (atomics into out)
    edge_kernel<<<N_EDGES / 32, 384, 0, stream>>>(
        x, mu, ei, rbf, uv, cut, Wf1, bf1, Wf2, bf2, out_q, out_mu);
}

// Round 2
// 891.398 us; speedup vs baseline: 2.1901x; 2.1901x over previous
//
#include <hip/hip_runtime.h>
#include <math.h>

#define N_NODES 10000
#define N_EDGES 320000
#define HIDDEN  128
#define NUM_RBF 20
#define H3      384   // 3*HIDDEN
#define FS_PAD  388   // f_s row pad: 776B stride -> 4-row groups land on distinct banks

typedef __attribute__((ext_vector_type(8))) short short8;
typedef __attribute__((ext_vector_type(4))) float floatx4;

__device__ __forceinline__ float b2f(ushort u) {
    unsigned v = ((unsigned)u) << 16; float f; __builtin_memcpy(&f, &v, 4); return f;
}
__device__ __forceinline__ ushort f2b(float f) {   // RNE f32 -> bf16
    unsigned x; __builtin_memcpy(&x, &f, 4);
    return (ushort)((x + 0x7fffu + ((x >> 16) & 1u)) >> 16);
}

// ---------------------------------------------------------------------------
// Kernel 1: out = concat(q, mu)   (float4 copy)
// ---------------------------------------------------------------------------
__global__ void copy_init_kernel(const float4* __restrict__ q,
                                 const float4* __restrict__ mu,
                                 float4* __restrict__ out) {
    const int n_q4  = N_NODES * HIDDEN / 4;
    const int n_mu4 = N_NODES * 3 * HIDDEN / 4;
    const int stride = gridDim.x * blockDim.x;
    const int tid = blockIdx.x * blockDim.x + threadIdx.x;
    for (int i = tid; i < n_q4; i += stride)  out[i] = q[i];
    for (int i = tid; i < n_mu4; i += stride) out[n_q4 + i] = mu[i];
}

// ---------------------------------------------------------------------------
// Kernel 1b: Wf2 [128][384] f32 -> bf16 in MFMA-B fragment-linear layout:
//   dst[(((kt*24 + nt)*64 + lane)*8 + b] = Wf2[kt*32 + (lane>>4)*8 + b][nt*16 + (lane&15)]
// so the edge kernel's lane reads one coalesced 16B short8 per (kt, nt).
// ---------------------------------------------------------------------------
__global__ void wf2_prep_kernel(const float* __restrict__ Wf2,
                                ushort* __restrict__ Wf2b) {
    const int idx = blockIdx.x * blockDim.x + threadIdx.x;   // over 128*384
    if (idx >= HIDDEN * H3) return;
    const int k = idx / H3, j = idx % H3;
    const int kt = k >> 5, r = k & 31;
    const int hi = r >> 3, b = r & 7;
    const int nt = j >> 4, jj = j & 15;
    const int lane = hi * 16 + jj;
    Wf2b[(((kt * 24 + nt) * 64) + lane) * 8 + b] = f2b(Wf2[k * H3 + j]);
}

// ---------------------------------------------------------------------------
// Kernel 2: node MLP  x = silu(q@W1 + b1) @ W2 + b2  -> bf16 x [N][384] in ws
// ---------------------------------------------------------------------------
__global__ __launch_bounds__(384) void node_mlp_kernel(
    const float* __restrict__ q,
    const float* __restrict__ W1, const float* __restrict__ b1,
    const float* __restrict__ W2, const float* __restrict__ b2,
    ushort* __restrict__ x_h) {

    __shared__ float q_s[32][HIDDEN];
    __shared__ float h_s[32][H3];

    const int n0 = blockIdx.x * 32;
    const int nt = min(32, N_NODES - n0);
    const int t  = threadIdx.x;
    const int j  = t;

    for (int idx = t; idx < 32 * HIDDEN; idx += 384) {
        const int i = idx >> 7, k = idx & 127;
        q_s[i][k] = (i < nt) ? q[(n0 + i) * HIDDEN + k] : 0.0f;
    }
    __syncthreads();

    {
        const float bb = b1[j];
        const float* wp = W1 + j;
        for (int i0 = 0; i0 < 32; i0 += 16) {
            float acc[16];
#pragma unroll
            for (int u = 0; u < 16; ++u) acc[u] = bb;
            for (int k4 = 0; k4 < HIDDEN / 4; ++k4) {
                const float w0 = wp[(4 * k4 + 0) * H3];
                const float w1 = wp[(4 * k4 + 1) * H3];
                const float w2 = wp[(4 * k4 + 2) * H3];
                const float w3 = wp[(4 * k4 + 3) * H3];
#pragma unroll
                for (int u = 0; u < 16; ++u) {
                    const float4 h4 =
                        reinterpret_cast<const float4*>(&q_s[i0 + u][0])[k4];
                    acc[u] = fmaf(h4.x, w0, acc[u]);
                    acc[u] = fmaf(h4.y, w1, acc[u]);
                    acc[u] = fmaf(h4.z, w2, acc[u]);
                    acc[u] = fmaf(h4.w, w3, acc[u]);
                }
            }
#pragma unroll
            for (int u = 0; u < 16; ++u) {
                const float v = acc[u];
                h_s[i0 + u][j] = v / (1.0f + __expf(-v));
            }
        }
    }
    __syncthreads();

    {
        const float bb = b2[j];
        const float* wp = W2 + j;
        for (int i0 = 0; i0 < 32; i0 += 16) {
            float acc[16];
#pragma unroll
            for (int u = 0; u < 16; ++u) acc[u] = bb;
            for (int k4 = 0; k4 < H3 / 4; ++k4) {
                const float w0 = wp[(4 * k4 + 0) * H3];
                const float w1 = wp[(4 * k4 + 1) * H3];
                const float w2 = wp[(4 * k4 + 2) * H3];
                const float w3 = wp[(4 * k4 + 3) * H3];
#pragma unroll
                for (int u = 0; u < 16; ++u) {
                    const float4 h4 =
                        reinterpret_cast<const float4*>(&h_s[i0 + u][0])[k4];
                    acc[u] = fmaf(h4.x, w0, acc[u]);
                    acc[u] = fmaf(h4.y, w1, acc[u]);
                    acc[u] = fmaf(h4.z, w2, acc[u]);
                    acc[u] = fmaf(h4.w, w3, acc[u]);
                }
            }
#pragma unroll
            for (int u = 0; u < 16; ++u) {
                if (i0 + u < nt) x_h[(n0 + i0 + u) * H3 + j] = f2b(acc[u]);
            }
        }
    }
}

// ---------------------------------------------------------------------------
// Kernel 3: fused edge filter MLP (MFMA) + gather-multiply-scatter
// 256 threads (4 waves), 32 edges/block, grid = 10000.
// ---------------------------------------------------------------------------
__global__ __launch_bounds__(256) void edge_kernel(
    const ushort* __restrict__ x_h,       // [N,384] bf16 from node MLP
    const float*  __restrict__ mu,        // [N,3,128] f32
    const int*    __restrict__ ei,        // [2,E]: row0=target, row1=source
    const float*  __restrict__ rbf,       // [E,20]
    const float*  __restrict__ uv,        // [E,3]
    const float*  __restrict__ cut,       // [E]
    const float*  __restrict__ Wf1, const float* __restrict__ bf1,
    const ushort* __restrict__ Wf2b,      // frag-linear bf16 Wf2
    const float*  __restrict__ bf2,
    float* __restrict__ out_q,            // [N,128]   pre-init to q
    float* __restrict__ out_mu) {         // [N,3,128] pre-init to mu

    __shared__ float  rbf_s[32][NUM_RBF];      // 2.5 KB
    __shared__ ushort h1_s[32 * HIDDEN];       // 8 KB, bf16, XOR-swizzled rows
    __shared__ ushort f_s[32][FS_PAD];         // 24.25 KB, bf16 filters
    __shared__ int    src_s[32], tgt_s[32];
    __shared__ float  uv_s[32][3], cut_s[32];

    const int e0 = blockIdx.x * 32;
    const int t  = threadIdx.x;

    // ---- stage per-edge small data ----
    for (int idx = t; idx < 32 * NUM_RBF; idx += 256)
        rbf_s[idx / NUM_RBF][idx % NUM_RBF] = rbf[e0 * NUM_RBF + idx];
    if (t < 32) {
        tgt_s[t] = ei[e0 + t];
        src_s[t] = ei[N_EDGES + e0 + t];
        cut_s[t] = cut[e0 + t];
    } else if (t < 32 + 96) {
        const int u = t - 32;
        uv_s[u / 3][u % 3] = uv[e0 * 3 + u];
    }
    __syncthreads();

    // ---- filter layer 1 (f32 VALU): [32,20]@[20,128] -> silu -> bf16 LDS ----
    {
        const int col = t & 127;
        const int grp = t >> 7;                 // 0..1
        const float bb = bf1[col];
        for (int i = grp; i < 32; i += 2) {
            float acc = bb;
#pragma unroll
            for (int k = 0; k < NUM_RBF; ++k)
                acc = fmaf(rbf_s[i][k], Wf1[k * HIDDEN + col], acc);
            const float h = acc / (1.0f + __expf(-acc));
            const int byte = i * 256 + (((col << 1)) ^ ((i & 7) << 4));
            h1_s[byte >> 1] = f2b(h);
        }
    }
    __syncthreads();

    // ---- filter layer 2 via MFMA: [32,128] @ [128,384] ----
    {
        const int wv   = t >> 6;                // 0..3, owns cols [wv*96, wv*96+96)
        const int lane = t & 63;
        const int lr   = lane & 15;             // row/col within 16-tile
        const int lh   = lane >> 4;             // k-group 0..3

        floatx4 acc[2][6];
#pragma unroll
        for (int m = 0; m < 2; ++m)
#pragma unroll
            for (int n = 0; n < 6; ++n) acc[m][n] = (floatx4){0.f, 0.f, 0.f, 0.f};

#pragma unroll
        for (int kt = 0; kt < 4; ++kt) {
            const int kbyte = kt * 64 + lh * 16;
            const int r0 = lr, r1 = 16 + lr;
            const int b0 = r0 * 256 + (kbyte ^ ((r0 & 7) << 4));
            const int b1 = r1 * 256 + (kbyte ^ ((r1 & 7) << 4));
            const short8 a0 = *reinterpret_cast<const short8*>(&h1_s[b0 >> 1]);
            const short8 a1 = *reinterpret_cast<const short8*>(&h1_s[b1 >> 1]);
#pragma unroll
            for (int nt = 0; nt < 6; ++nt) {
                const short8 b = *reinterpret_cast<const short8*>(
                    &Wf2b[(((kt * 24) + (wv * 6 + nt)) * 64 + lane) * 8]);
                acc[0][nt] = __builtin_amdgcn_mfma_f32_16x16x32_bf16(
                    a0, b, acc[0][nt], 0, 0, 0);
                acc[1][nt] = __builtin_amdgcn_mfma_f32_16x16x32_bf16(
                    a1, b, acc[1][nt], 0, 0, 0);
            }
        }

        // epilogue: + bf2, * cutoff, store bf16 filters to LDS
#pragma unroll
        for (int nt = 0; nt < 6; ++nt) {
            const int c = wv * 96 + nt * 16 + lr;
            const float bb = bf2[c];
#pragma unroll
            for (int m = 0; m < 2; ++m) {
                const int rbase = m * 16 + lh * 4;
#pragma unroll
                for (int r = 0; r < 4; ++r) {
                    const int row = rbase + r;
                    f_s[row][c] = f2b((acc[m][nt][r] + bb) * cut_s[row]);
                }
            }
        }
    }
    __syncthreads();

    // ---- messages: gather x[src], mu[src]; scatter-add into out ----
    {
        const int c   = t & 127;
        const int grp = t >> 7;                 // 0..1
        for (int i = grp; i < 32; i += 2) {
            const int src = src_s[i];
            const int tgt = tgt_s[i];
            const ushort* xp = x_h + src * H3;
            const float xq = b2f(xp[c]);
            const float xr = b2f(xp[HIDDEN + c]);
            const float xm = b2f(xp[2 * HIDDEN + c]);
            const float fq = b2f(f_s[i][c]);
            const float fr = b2f(f_s[i][HIDDEN + c]);
            const float fm = b2f(f_s[i][2 * HIDDEN + c]);

            atomicAdd(&out_q[tgt * HIDDEN + c], xq * fq);

            const float xrr = xr * fr;
            const float xmm = xm * fm;
            atomicAdd(&out_mu[(tgt * 3 + 0) * HIDDEN + c],
                      fmaf(uv_s[i][0], xrr, mu[(src * 3 + 0) * HIDDEN + c] * xmm));
            atomicAdd(&out_mu[(tgt * 3 + 1) * HIDDEN + c],
                      fmaf(uv_s[i][1], xrr, mu[(src * 3 + 1) * HIDDEN + c] * xmm));
            atomicAdd(&out_mu[(tgt * 3 + 2) * HIDDEN + c],
                      fmaf(uv_s[i][2], xrr, mu[(src * 3 + 2) * HIDDEN + c] * xmm));
        }
    }
}

// ---------------------------------------------------------------------------
extern "C" void kernel_launch(void* const* d_in, const int* in_sizes, int n_in,
                              void* d_out, int out_size, void* d_ws, size_t ws_size,
                              hipStream_t stream) {
    const float* q   = (const float*)d_in[0];
    const float* mu  = (const float*)d_in[1];
    const int*   ei  = (const int*)  d_in[2];
    const float* rbf = (const float*)d_in[3];
    const float* uv  = (const float*)d_in[4];
    const float* cut = (const float*)d_in[5];
    const float* W1  = (const float*)d_in[6];
    const float* b1  = (const float*)d_in[7];
    const float* W2  = (const float*)d_in[8];
    const float* b2  = (const float*)d_in[9];
    const float* Wf1 = (const float*)d_in[10];
    const float* bf1 = (const float*)d_in[11];
    const float* Wf2 = (const float*)d_in[12];
    const float* bf2 = (const float*)d_in[13];

    float* out    = (float*)d_out;
    float* out_q  = out;
    float* out_mu = out + N_NODES * HIDDEN;

    ushort* Wf2b = (ushort*)d_ws;                        // 96 KB frag-linear bf16
    ushort* x_h  = (ushort*)((char*)d_ws + 98304);       // [N,384] bf16 (7.68 MB)

    copy_init_kernel<<<1280, 256, 0, stream>>>(
        (const float4*)q, (const float4*)mu, (float4*)d_out);

    wf2_prep_kernel<<<(HIDDEN * H3 + 255) / 256, 256, 0, stream>>>(Wf2, Wf2b);

    node_mlp_kernel<<<(N_NODES + 31) / 32, 384, 0, stream>>>(
        q, W1, b1, W2, b2, x_h);

    edge_kernel<<<N_EDGES / 32, 256, 0, stream>>>(
        x_h, mu, ei, rbf, uv, cut, Wf1, bf1, Wf2b, bf2, out_q, out_mu);
}

// Round 4
// 586.922 us; speedup vs baseline: 3.3262x; 1.5188x over previous
//
#include <hip/hip_runtime.h>
#include <math.h>

#define N_NODES 10000
#define N_EDGES 320000
#define HIDDEN  128
#define NUM_RBF 20
#define H3      384   // 3*HIDDEN
#define FS_PAD  388   // f_s row pad (bf16 elems): 776B stride

typedef __attribute__((ext_vector_type(8))) short short8;
typedef __attribute__((ext_vector_type(4))) float floatx4;

__device__ __forceinline__ float b2f(ushort u) {
    unsigned v = ((unsigned)u) << 16; float f; __builtin_memcpy(&f, &v, 4); return f;
}
__device__ __forceinline__ ushort f2b(float f) {   // RNE f32 -> bf16
    unsigned x; __builtin_memcpy(&x, &f, 4);
    return (ushort)((x + 0x7fffu + ((x >> 16) & 1u)) >> 16);
}

// ---------------------------------------------------------------------------
// Kernel 1: out = concat(q, mu)   (float4 copy)
// ---------------------------------------------------------------------------
__global__ void copy_init_kernel(const float4* __restrict__ q,
                                 const float4* __restrict__ mu,
                                 float4* __restrict__ out) {
    const int n_q4  = N_NODES * HIDDEN / 4;
    const int n_mu4 = N_NODES * 3 * HIDDEN / 4;
    const int stride = gridDim.x * blockDim.x;
    const int tid = blockIdx.x * blockDim.x + threadIdx.x;
    for (int i = tid; i < n_q4; i += stride)  out[i] = q[i];
    for (int i = tid; i < n_mu4; i += stride) out[n_q4 + i] = mu[i];
}

// ---------------------------------------------------------------------------
// Kernel 1b: Wf2 [128][384] f32 -> bf16 MFMA-B fragment-linear layout.
// ---------------------------------------------------------------------------
__global__ void wf2_prep_kernel(const float* __restrict__ Wf2,
                                ushort* __restrict__ Wf2b) {
    const int idx = blockIdx.x * blockDim.x + threadIdx.x;
    if (idx >= HIDDEN * H3) return;
    const int k = idx / H3, j = idx % H3;
    const int kt = k >> 5, r = k & 31;
    const int hi = r >> 3, b = r & 7;
    const int nt = j >> 4, jj = j & 15;
    const int lane = hi * 16 + jj;
    Wf2b[(((kt * 24 + nt) * 64) + lane) * 8 + b] = f2b(Wf2[k * H3 + j]);
}

// ---------------------------------------------------------------------------
// CSR build: zero counts -> histogram -> scan(+cursor) -> scatter perm
// ---------------------------------------------------------------------------
__global__ void zero_counts_kernel(int* __restrict__ counts) {
    const int i = blockIdx.x * blockDim.x + threadIdx.x;
    if (i < N_NODES) counts[i] = 0;
}

__global__ void hist_kernel(const int* __restrict__ ei, int* __restrict__ counts) {
    const int i = blockIdx.x * blockDim.x + threadIdx.x;
    if (i < N_EDGES) atomicAdd(&counts[ei[i]], 1);   // row 0 = target
}

#define SCAN_NT 1024
#define SCAN_CHUNK 10   // 1024*10 = 10240 >= N_NODES
__global__ __launch_bounds__(SCAN_NT) void scan_kernel(
    const int* __restrict__ counts, int* __restrict__ cursor) {
    __shared__ int s[SCAN_NT];
    const int t = threadIdx.x;
    const int base = t * SCAN_CHUNK;
    int local[SCAN_CHUNK];
    int sum = 0;
#pragma unroll
    for (int i = 0; i < SCAN_CHUNK; ++i) {
        const int idx = base + i;
        const int v = (idx < N_NODES) ? counts[idx] : 0;
        local[i] = sum;
        sum += v;
    }
    s[t] = sum;
    __syncthreads();
    for (int d = 1; d < SCAN_NT; d <<= 1) {
        const int v = (t >= d) ? s[t - d] : 0;
        __syncthreads();
        s[t] += v;
        __syncthreads();
    }
    const int excl = (t == 0) ? 0 : s[t - 1];
#pragma unroll
    for (int i = 0; i < SCAN_CHUNK; ++i) {
        const int idx = base + i;
        if (idx < N_NODES) cursor[idx] = excl + local[i];
    }
}

__global__ void scatter_kernel(const int* __restrict__ ei,
                               int* __restrict__ cursor,
                               int* __restrict__ perm) {
    const int i = blockIdx.x * blockDim.x + threadIdx.x;
    if (i < N_EDGES) {
        const int t = ei[i];
        const int pos = atomicAdd(&cursor[t], 1);
        perm[pos] = i;
    }
}

// identity perm fallback (ws too small for CSR build)
__global__ void iota_kernel(int* __restrict__ perm) {
    const int i = blockIdx.x * blockDim.x + threadIdx.x;
    if (i < N_EDGES) perm[i] = i;
}

// ---------------------------------------------------------------------------
// Kernel 2: node MLP  x = silu(q@W1 + b1) @ W2 + b2  -> bf16 x [N][384] in ws
// ---------------------------------------------------------------------------
__global__ __launch_bounds__(384) void node_mlp_kernel(
    const float* __restrict__ q,
    const float* __restrict__ W1, const float* __restrict__ b1,
    const float* __restrict__ W2, const float* __restrict__ b2,
    ushort* __restrict__ x_h) {

    __shared__ float q_s[32][HIDDEN];
    __shared__ float h_s[32][H3];

    const int n0 = blockIdx.x * 32;
    const int nt = min(32, N_NODES - n0);
    const int t  = threadIdx.x;
    const int j  = t;

    for (int idx = t; idx < 32 * HIDDEN; idx += 384) {
        const int i = idx >> 7, k = idx & 127;
        q_s[i][k] = (i < nt) ? q[(n0 + i) * HIDDEN + k] : 0.0f;
    }
    __syncthreads();

    {
        const float bb = b1[j];
        const float* wp = W1 + j;
        for (int i0 = 0; i0 < 32; i0 += 16) {
            float acc[16];
#pragma unroll
            for (int u = 0; u < 16; ++u) acc[u] = bb;
            for (int k4 = 0; k4 < HIDDEN / 4; ++k4) {
                const float w0 = wp[(4 * k4 + 0) * H3];
                const float w1 = wp[(4 * k4 + 1) * H3];
                const float w2 = wp[(4 * k4 + 2) * H3];
                const float w3 = wp[(4 * k4 + 3) * H3];
#pragma unroll
                for (int u = 0; u < 16; ++u) {
                    const float4 h4 =
                        reinterpret_cast<const float4*>(&q_s[i0 + u][0])[k4];
                    acc[u] = fmaf(h4.x, w0, acc[u]);
                    acc[u] = fmaf(h4.y, w1, acc[u]);
                    acc[u] = fmaf(h4.z, w2, acc[u]);
                    acc[u] = fmaf(h4.w, w3, acc[u]);
                }
            }
#pragma unroll
            for (int u = 0; u < 16; ++u) {
                const float v = acc[u];
                h_s[i0 + u][j] = v / (1.0f + __expf(-v));
            }
        }
    }
    __syncthreads();

    {
        const float bb = b2[j];
        const float* wp = W2 + j;
        for (int i0 = 0; i0 < 32; i0 += 16) {
            float acc[16];
#pragma unroll
            for (int u = 0; u < 16; ++u) acc[u] = bb;
            for (int k4 = 0; k4 < H3 / 4; ++k4) {
                const float w0 = wp[(4 * k4 + 0) * H3];
                const float w1 = wp[(4 * k4 + 1) * H3];
                const float w2 = wp[(4 * k4 + 2) * H3];
                const float w3 = wp[(4 * k4 + 3) * H3];
#pragma unroll
                for (int u = 0; u < 16; ++u) {
                    const float4 h4 =
                        reinterpret_cast<const float4*>(&h_s[i0 + u][0])[k4];
                    acc[u] = fmaf(h4.x, w0, acc[u]);
                    acc[u] = fmaf(h4.y, w1, acc[u]);
                    acc[u] = fmaf(h4.z, w2, acc[u]);
                    acc[u] = fmaf(h4.w, w3, acc[u]);
                }
            }
#pragma unroll
            for (int u = 0; u < 16; ++u) {
                if (i0 + u < nt) x_h[(n0 + i0 + u) * H3 + j] = f2b(acc[u]);
            }
        }
    }
}

// ---------------------------------------------------------------------------
// Kernel 3: fused edge filter MLP (MFMA) + sorted-edge segment reduction.
// 512 threads (8 waves), 32 target-sorted edges/block, grid = 10000.
// ---------------------------------------------------------------------------
__global__ __launch_bounds__(512) void edge_kernel(
    const ushort* __restrict__ x_h,       // [N,384] bf16 from node MLP
    const float*  __restrict__ mu,        // [N,3,128] f32
    const int*    __restrict__ ei,        // [2,E]: row0=target, row1=source
    const int*    __restrict__ perm,      // [E] edge ids sorted by target
    const float*  __restrict__ rbf,       // [E,20]
    const float*  __restrict__ uv,        // [E,3]
    const float*  __restrict__ cut,       // [E]
    const float*  __restrict__ Wf1, const float* __restrict__ bf1,
    const ushort* __restrict__ Wf2b,      // frag-linear bf16 Wf2
    const float*  __restrict__ bf2,
    float* __restrict__ out_q,            // [N,128]   pre-init to q
    float* __restrict__ out_mu) {         // [N,3,128] pre-init to mu

    __shared__ float  rbf_s[32][NUM_RBF];
    __shared__ ushort h1_s[32 * HIDDEN];       // bf16, XOR-swizzled rows
    __shared__ ushort f_s[32][FS_PAD];         // bf16 filters
    __shared__ int    eid_s[32], src_s[32], tgt_s[32];
    __shared__ float  uv_s[32][3], cut_s[32];

    const int e0 = blockIdx.x * 32;
    const int t  = threadIdx.x;

    // ---- stage per-edge small data (perm-indexed) ----
    if (t < 32) {
        const int eid = perm[e0 + t];
        eid_s[t] = eid;
        tgt_s[t] = ei[eid];
        src_s[t] = ei[N_EDGES + eid];
        cut_s[t] = cut[eid];
        uv_s[t][0] = uv[eid * 3 + 0];
        uv_s[t][1] = uv[eid * 3 + 1];
        uv_s[t][2] = uv[eid * 3 + 2];
    }
    __syncthreads();
    for (int idx = t; idx < 32 * NUM_RBF; idx += 512) {
        const int i = idx / NUM_RBF, k = idx % NUM_RBF;
        rbf_s[i][k] = rbf[eid_s[i] * NUM_RBF + k];
    }
    __syncthreads();

    // ---- filter layer 1 (f32 VALU): [32,20]@[20,128] -> silu -> bf16 LDS ----
    {
        const int col = t & 127;
        const int grp = t >> 7;                 // 0..3
        const float bb = bf1[col];
        for (int i = grp; i < 32; i += 4) {
            float acc = bb;
#pragma unroll
            for (int k = 0; k < NUM_RBF; ++k)
                acc = fmaf(rbf_s[i][k], Wf1[k * HIDDEN + col], acc);
            const float h = acc / (1.0f + __expf(-acc));
            const int byte = i * 256 + (((col << 1)) ^ ((i & 7) << 4));
            h1_s[byte >> 1] = f2b(h);
        }
    }
    __syncthreads();

    // ---- filter layer 2 via MFMA: [32,128] @ [128,384] ----
    {
        const int wv   = t >> 6;                // 0..7, owns 3 col-tiles
        const int lane = t & 63;
        const int lr   = lane & 15;
        const int lh   = lane >> 4;

        floatx4 acc[2][3];
#pragma unroll
        for (int m = 0; m < 2; ++m)
#pragma unroll
            for (int n = 0; n < 3; ++n) acc[m][n] = (floatx4){0.f, 0.f, 0.f, 0.f};

#pragma unroll
        for (int kt = 0; kt < 4; ++kt) {
            const int kbyte = kt * 64 + lh * 16;
            const int r0 = lr, r1 = 16 + lr;
            const int b0 = r0 * 256 + (kbyte ^ ((r0 & 7) << 4));
            const int b1 = r1 * 256 + (kbyte ^ ((r1 & 7) << 4));
            const short8 a0 = *reinterpret_cast<const short8*>(&h1_s[b0 >> 1]);
            const short8 a1 = *reinterpret_cast<const short8*>(&h1_s[b1 >> 1]);
#pragma unroll
            for (int n = 0; n < 3; ++n) {
                const int tile = wv * 3 + n;
                const short8 b = *reinterpret_cast<const short8*>(
                    &Wf2b[(((kt * 24) + tile) * 64 + lane) * 8]);
                acc[0][n] = __builtin_amdgcn_mfma_f32_16x16x32_bf16(
                    a0, b, acc[0][n], 0, 0, 0);
                acc[1][n] = __builtin_amdgcn_mfma_f32_16x16x32_bf16(
                    a1, b, acc[1][n], 0, 0, 0);
            }
        }

        // epilogue: + bf2, * cutoff, store bf16 filters to LDS
#pragma unroll
        for (int n = 0; n < 3; ++n) {
            const int c = (wv * 3 + n) * 16 + lr;
            const float bb = bf2[c];
#pragma unroll
            for (int m = 0; m < 2; ++m) {
                const int rbase = m * 16 + lh * 4;
#pragma unroll
                for (int r = 0; r < 4; ++r) {
                    const int row = rbase + r;
                    f_s[row][c] = f2b((acc[m][n][r] + bb) * cut_s[row]);
                }
            }
        }
    }
    __syncthreads();

    // ---- sorted segment reduction: register acc, flush on target change ----
    {
        const int c    = t & 127;
        const int part = t >> 7;                // 0: q, 1..3: mu components
        float acc = 0.0f;
        int cur = tgt_s[0];
        for (int i = 0; i < 32; ++i) {
            const int tgt = tgt_s[i];
            if (tgt != cur) {                   // block-uniform branch
                if (part == 0) atomicAdd(&out_q[cur * HIDDEN + c], acc);
                else atomicAdd(&out_mu[(cur * 3 + (part - 1)) * HIDDEN + c], acc);
                acc = 0.0f;
                cur = tgt;
            }
            const int src = src_s[i];
            const ushort* xp = x_h + src * H3;
            if (part == 0) {                    // wave-uniform branch
                acc = fmaf(b2f(xp[c]), b2f(f_s[i][c]), acc);
            } else {
                const int d = part - 1;
                const float xrr = b2f(xp[HIDDEN + c]) * b2f(f_s[i][HIDDEN + c]);
                const float xmm = b2f(xp[2 * HIDDEN + c]) * b2f(f_s[i][2 * HIDDEN + c]);
                acc += fmaf(uv_s[i][d], xrr, mu[(src * 3 + d) * HIDDEN + c] * xmm);
            }
        }
        if (part == 0) atomicAdd(&out_q[cur * HIDDEN + c], acc);
        else atomicAdd(&out_mu[(cur * 3 + (part - 1)) * HIDDEN + c], acc);
    }
}

// ---------------------------------------------------------------------------
extern "C" void kernel_launch(void* const* d_in, const int* in_sizes, int n_in,
                              void* d_out, int out_size, void* d_ws, size_t ws_size,
                              hipStream_t stream) {
    const float* q   = (const float*)d_in[0];
    const float* mu  = (const float*)d_in[1];
    const int*   ei  = (const int*)  d_in[2];
    const float* rbf = (const float*)d_in[3];
    const float* uv  = (const float*)d_in[4];
    const float* cut = (const float*)d_in[5];
    const float* W1  = (const float*)d_in[6];
    const float* b1  = (const float*)d_in[7];
    const float* W2  = (const float*)d_in[8];
    const float* b2  = (const float*)d_in[9];
    const float* Wf1 = (const float*)d_in[10];
    const float* bf1 = (const float*)d_in[11];
    const float* Wf2 = (const float*)d_in[12];
    const float* bf2 = (const float*)d_in[13];

    float* out    = (float*)d_out;
    float* out_q  = out;
    float* out_mu = out + N_NODES * HIDDEN;

    // ws layout (bytes):
    //   [0, 96K)        Wf2b
    //   [96K, +1.28MB)  perm
    //   [.., +40KB)     counts
    //   [.., +40KB)     cursor
    //   [.., +7.68MB)   x_h
    char* ws = (char*)d_ws;
    size_t off = 0;
    ushort* Wf2b   = (ushort*)(ws + off); off += 98304;
    int*    perm   = (int*)   (ws + off); off += (size_t)N_EDGES * 4;
    int*    counts = (int*)   (ws + off); off += (size_t)N_NODES * 4 + 1024;
    int*    cursor = (int*)   (ws + off); off += (size_t)N_NODES * 4 + 1024;
    ushort* x_h    = (ushort*)(ws + off); off += (size_t)N_NODES * H3 * 2;
    const bool ws_ok = (off <= ws_size);   // constant across calls (same args)

    copy_init_kernel<<<1280, 256, 0, stream>>>(
        (const float4*)q, (const float4*)mu, (float4*)d_out);

    wf2_prep_kernel<<<(HIDDEN * H3 + 255) / 256, 256, 0, stream>>>(Wf2, Wf2b);

    if (ws_ok) {
        // CSR build: perm = edge ids sorted by target
        zero_counts_kernel<<<(N_NODES + 255) / 256, 256, 0, stream>>>(counts);
        hist_kernel<<<(N_EDGES + 255) / 256, 256, 0, stream>>>(ei, counts);
        scan_kernel<<<1, SCAN_NT, 0, stream>>>(counts, cursor);
        scatter_kernel<<<(N_EDGES + 255) / 256, 256, 0, stream>>>(ei, cursor, perm);
    } else {
        iota_kernel<<<(N_EDGES + 255) / 256, 256, 0, stream>>>(perm);
    }

    node_mlp_kernel<<<(N_NODES + 31) / 32, 384, 0, stream>>>(
        q, W1, b1, W2, b2, x_h);

    edge_kernel<<<N_EDGES / 32, 512, 0, stream>>>(
        x_h, mu, ei, perm, rbf, uv, cut, Wf1, bf1, Wf2b, bf2, out_q, out_mu);
}

// Round 5
// 367.334 us; speedup vs baseline: 5.3146x; 1.5978x over previous
//
#include <hip/hip_runtime.h>
#include <math.h>

#define N_NODES 10000
#define N_EDGES 320000
#define HIDDEN  128
#define NUM_RBF 20
#define H3      384   // 3*HIDDEN

typedef __attribute__((ext_vector_type(8))) short short8;
typedef __attribute__((ext_vector_type(4))) float floatx4;

__device__ __forceinline__ float b2f(ushort u) {
    unsigned v = ((unsigned)u) << 16; float f; __builtin_memcpy(&f, &v, 4); return f;
}
__device__ __forceinline__ ushort f2b(float f) {   // RNE f32 -> bf16
    unsigned x; __builtin_memcpy(&x, &f, 4);
    return (ushort)((x + 0x7fffu + ((x >> 16) & 1u)) >> 16);
}

// ---------------------------------------------------------------------------
// Kernel 1: out = concat(q, mu)   (float4 copy)
// ---------------------------------------------------------------------------
__global__ void copy_init_kernel(const float4* __restrict__ q,
                                 const float4* __restrict__ mu,
                                 float4* __restrict__ out) {
    const int n_q4  = N_NODES * HIDDEN / 4;
    const int n_mu4 = N_NODES * 3 * HIDDEN / 4;
    const int stride = gridDim.x * blockDim.x;
    const int tid = blockIdx.x * blockDim.x + threadIdx.x;
    for (int i = tid; i < n_q4; i += stride)  out[i] = q[i];
    for (int i = tid; i < n_mu4; i += stride) out[n_q4 + i] = mu[i];
}

// ---------------------------------------------------------------------------
// Generic weight prep: W [K][384] f32 -> bf16 MFMA-B fragment-linear layout
//   dst[(((kt*24 + nt)*64 + lane)*8 + b] = W[kt*32 + (lane>>4)*8 + b][nt*16 + (lane&15)]
// ---------------------------------------------------------------------------
__global__ void w_prep_kernel(const float* __restrict__ W,
                              ushort* __restrict__ Wb, int K) {
    const int idx = blockIdx.x * blockDim.x + threadIdx.x;
    if (idx >= K * H3) return;
    const int k = idx / H3, j = idx % H3;
    const int kt = k >> 5, r = k & 31;
    const int hi = r >> 3, b = r & 7;
    const int nt = j >> 4, jj = j & 15;
    const int lane = hi * 16 + jj;
    Wb[(((kt * 24 + nt) * 64) + lane) * 8 + b] = f2b(W[k * H3 + j]);
}

// ---------------------------------------------------------------------------
// CSR build: zero counts -> histogram -> scan(+cursor) -> scatter perm
// ---------------------------------------------------------------------------
__global__ void zero_counts_kernel(int* __restrict__ counts) {
    const int i = blockIdx.x * blockDim.x + threadIdx.x;
    if (i < N_NODES) counts[i] = 0;
}

__global__ void hist_kernel(const int* __restrict__ ei, int* __restrict__ counts) {
    const int i = blockIdx.x * blockDim.x + threadIdx.x;
    if (i < N_EDGES) atomicAdd(&counts[ei[i]], 1);   // row 0 = target
}

#define SCAN_NT 1024
#define SCAN_CHUNK 10   // 1024*10 = 10240 >= N_NODES
__global__ __launch_bounds__(SCAN_NT) void scan_kernel(
    const int* __restrict__ counts, int* __restrict__ cursor) {
    __shared__ int s[SCAN_NT];
    const int t = threadIdx.x;
    const int base = t * SCAN_CHUNK;
    int local[SCAN_CHUNK];
    int sum = 0;
#pragma unroll
    for (int i = 0; i < SCAN_CHUNK; ++i) {
        const int idx = base + i;
        const int v = (idx < N_NODES) ? counts[idx] : 0;
        local[i] = sum;
        sum += v;
    }
    s[t] = sum;
    __syncthreads();
    for (int d = 1; d < SCAN_NT; d <<= 1) {
        const int v = (t >= d) ? s[t - d] : 0;
        __syncthreads();
        s[t] += v;
        __syncthreads();
    }
    const int excl = (t == 0) ? 0 : s[t - 1];
#pragma unroll
    for (int i = 0; i < SCAN_CHUNK; ++i) {
        const int idx = base + i;
        if (idx < N_NODES) cursor[idx] = excl + local[i];
    }
}

__global__ void scatter_kernel(const int* __restrict__ ei,
                               int* __restrict__ cursor,
                               int* __restrict__ perm) {
    const int i = blockIdx.x * blockDim.x + threadIdx.x;
    if (i < N_EDGES) {
        const int t = ei[i];
        const int pos = atomicAdd(&cursor[t], 1);
        perm[pos] = i;
    }
}

// identity perm fallback (ws too small for CSR build)
__global__ void iota_kernel(int* __restrict__ perm) {
    const int i = blockIdx.x * blockDim.x + threadIdx.x;
    if (i < N_EDGES) perm[i] = i;
}

// ---------------------------------------------------------------------------
// Kernel 2: node MLP via MFMA.
// x_pack[n][c][0..2] = (x_q, x_r, x_mu) bf16;  [N][128][4] (4th pad unused).
// 512 threads (8 waves), 32 nodes/block.
// ---------------------------------------------------------------------------
__global__ __launch_bounds__(512) void node_mlp_kernel(
    const float*  __restrict__ q,
    const ushort* __restrict__ W1b, const float* __restrict__ b1,
    const ushort* __restrict__ W2b, const float* __restrict__ b2,
    ushort* __restrict__ x_pack) {

    __shared__ ushort q_s[32 * HIDDEN];   // 8 KB, 256B rows, XOR-swizzled
    __shared__ ushort h_s[32 * H3];       // 24 KB, 768B rows, XOR-swizzled

    const int n0 = blockIdx.x * 32;
    const int nt = min(32, N_NODES - n0);
    const int t  = threadIdx.x;

    // stage q -> bf16 swizzled
    for (int idx = t; idx < 32 * HIDDEN; idx += 512) {
        const int i = idx >> 7, k = idx & 127;
        const float v = (i < nt) ? q[(n0 + i) * HIDDEN + k] : 0.0f;
        const int byte = i * 256 + (((k << 1)) ^ ((i & 7) << 4));
        q_s[byte >> 1] = f2b(v);
    }
    __syncthreads();

    const int wv = t >> 6, lane = t & 63;
    const int lr = lane & 15, lh = lane >> 4;

    // ---- layer 1: [32,128] @ [128,384] -> silu -> h_s ----
    {
        floatx4 acc[2][3];
#pragma unroll
        for (int m = 0; m < 2; ++m)
#pragma unroll
            for (int n = 0; n < 3; ++n) acc[m][n] = (floatx4){0.f, 0.f, 0.f, 0.f};

#pragma unroll
        for (int kt = 0; kt < 4; ++kt) {
            const int kbyte = kt * 64 + lh * 16;
            const int r0 = lr, r1 = 16 + lr;
            const int b0 = r0 * 256 + (kbyte ^ ((r0 & 7) << 4));
            const int bb1 = r1 * 256 + (kbyte ^ ((r1 & 7) << 4));
            const short8 a0 = *reinterpret_cast<const short8*>(&q_s[b0 >> 1]);
            const short8 a1 = *reinterpret_cast<const short8*>(&q_s[bb1 >> 1]);
#pragma unroll
            for (int n = 0; n < 3; ++n) {
                const int tile = wv * 3 + n;
                const short8 b = *reinterpret_cast<const short8*>(
                    &W1b[(((kt * 24) + tile) * 64 + lane) * 8]);
                acc[0][n] = __builtin_amdgcn_mfma_f32_16x16x32_bf16(
                    a0, b, acc[0][n], 0, 0, 0);
                acc[1][n] = __builtin_amdgcn_mfma_f32_16x16x32_bf16(
                    a1, b, acc[1][n], 0, 0, 0);
            }
        }
#pragma unroll
        for (int n = 0; n < 3; ++n) {
            const int c = (wv * 3 + n) * 16 + lr;
            const float bb = b1[c];
#pragma unroll
            for (int m = 0; m < 2; ++m) {
#pragma unroll
                for (int r = 0; r < 4; ++r) {
                    const int row = m * 16 + lh * 4 + r;
                    const float v = acc[m][n][r] + bb;
                    const float s = v / (1.0f + __expf(-v));
                    const int byte = row * 768 + (((c << 1)) ^ ((row & 7) << 4));
                    h_s[byte >> 1] = f2b(s);
                }
            }
        }
    }
    __syncthreads();

    // ---- layer 2: [32,384] @ [384,384] -> x_pack ----
    {
        floatx4 acc[2][3];
#pragma unroll
        for (int m = 0; m < 2; ++m)
#pragma unroll
            for (int n = 0; n < 3; ++n) acc[m][n] = (floatx4){0.f, 0.f, 0.f, 0.f};

#pragma unroll
        for (int kt = 0; kt < 12; ++kt) {
            const int kbyte = kt * 64 + lh * 16;
            const int r0 = lr, r1 = 16 + lr;
            const int b0 = r0 * 768 + (kbyte ^ ((r0 & 7) << 4));
            const int bb1 = r1 * 768 + (kbyte ^ ((r1 & 7) << 4));
            const short8 a0 = *reinterpret_cast<const short8*>(&h_s[b0 >> 1]);
            const short8 a1 = *reinterpret_cast<const short8*>(&h_s[bb1 >> 1]);
#pragma unroll
            for (int n = 0; n < 3; ++n) {
                const int tile = wv * 3 + n;
                const short8 b = *reinterpret_cast<const short8*>(
                    &W2b[(((kt * 24) + tile) * 64 + lane) * 8]);
                acc[0][n] = __builtin_amdgcn_mfma_f32_16x16x32_bf16(
                    a0, b, acc[0][n], 0, 0, 0);
                acc[1][n] = __builtin_amdgcn_mfma_f32_16x16x32_bf16(
                    a1, b, acc[1][n], 0, 0, 0);
            }
        }
#pragma unroll
        for (int n = 0; n < 3; ++n) {
            const int c  = (wv * 3 + n) * 16 + lr;
            const int cc = c & 127, p = c >> 7;
            const float bb = b2[c];
#pragma unroll
            for (int m = 0; m < 2; ++m) {
#pragma unroll
                for (int r = 0; r < 4; ++r) {
                    const int row = m * 16 + lh * 4 + r;
                    if (row < nt)
                        x_pack[((size_t)(n0 + row) * 128 + cc) * 4 + p] =
                            f2b(acc[m][n][r] + bb);
                }
            }
        }
    }
}

// ---------------------------------------------------------------------------
// Kernel 3: fused edge filter MLP (MFMA) + sorted segment reduction.
// 512 threads; message phase = 128 channels x 4 edge-subtiles of 8 edges.
// ---------------------------------------------------------------------------
__global__ __launch_bounds__(512) void edge_kernel(
    const ushort* __restrict__ x_pack,    // [N][128][4] bf16 (xq,xr,xm,-)
    const float*  __restrict__ mu,        // [N,3,128] f32
    const int*    __restrict__ ei,        // [2,E]: row0=target, row1=source
    const int*    __restrict__ perm,      // [E] edge ids sorted by target
    const float*  __restrict__ rbf,       // [E,20]
    const float*  __restrict__ uv,        // [E,3]
    const float*  __restrict__ cut,       // [E]
    const float*  __restrict__ Wf1, const float* __restrict__ bf1,
    const ushort* __restrict__ Wf2b,      // frag-linear bf16 Wf2
    const float*  __restrict__ bf2,
    float* __restrict__ out_q,            // [N,128]   pre-init to q
    float* __restrict__ out_mu) {         // [N,3,128] pre-init to mu

    __shared__ float  rbf_s[32][NUM_RBF];     // 2.5 KB
    __shared__ ushort h1_s[32 * HIDDEN];      // 8 KB, XOR-swizzled
    __shared__ ushort f_pack[32 * HIDDEN * 4];// 32 KB: [32][128][4] (fq,fr,fm,-)
    __shared__ int    eid_s[32], src_s[32], tgt_s[32];
    __shared__ float  uv_s[32][3], cut_s[32];

    const int e0 = blockIdx.x * 32;
    const int t  = threadIdx.x;

    // ---- stage per-edge small data (perm-indexed) ----
    if (t < 32) {
        const int eid = perm[e0 + t];
        eid_s[t] = eid;
        tgt_s[t] = ei[eid];
        src_s[t] = ei[N_EDGES + eid];
        cut_s[t] = cut[eid];
        uv_s[t][0] = uv[eid * 3 + 0];
        uv_s[t][1] = uv[eid * 3 + 1];
        uv_s[t][2] = uv[eid * 3 + 2];
    }
    __syncthreads();
    for (int idx = t; idx < 32 * NUM_RBF; idx += 512) {
        const int i = idx / NUM_RBF, k = idx % NUM_RBF;
        rbf_s[i][k] = rbf[eid_s[i] * NUM_RBF + k];
    }
    __syncthreads();

    // ---- filter layer 1 (f32 VALU): [32,20]@[20,128] -> silu -> bf16 LDS ----
    {
        const int col = t & 127;
        const int grp = t >> 7;                 // 0..3
        const float bb = bf1[col];
        for (int i = grp; i < 32; i += 4) {
            float acc = bb;
#pragma unroll
            for (int k = 0; k < NUM_RBF; ++k)
                acc = fmaf(rbf_s[i][k], Wf1[k * HIDDEN + col], acc);
            const float h = acc / (1.0f + __expf(-acc));
            const int byte = i * 256 + (((col << 1)) ^ ((i & 7) << 4));
            h1_s[byte >> 1] = f2b(h);
        }
    }
    __syncthreads();

    // ---- filter layer 2 via MFMA: [32,128] @ [128,384] -> f_pack ----
    {
        const int wv   = t >> 6;                // 0..7, owns 3 col-tiles
        const int lane = t & 63;
        const int lr   = lane & 15;
        const int lh   = lane >> 4;

        floatx4 acc[2][3];
#pragma unroll
        for (int m = 0; m < 2; ++m)
#pragma unroll
            for (int n = 0; n < 3; ++n) acc[m][n] = (floatx4){0.f, 0.f, 0.f, 0.f};

#pragma unroll
        for (int kt = 0; kt < 4; ++kt) {
            const int kbyte = kt * 64 + lh * 16;
            const int r0 = lr, r1 = 16 + lr;
            const int b0 = r0 * 256 + (kbyte ^ ((r0 & 7) << 4));
            const int bb1 = r1 * 256 + (kbyte ^ ((r1 & 7) << 4));
            const short8 a0 = *reinterpret_cast<const short8*>(&h1_s[b0 >> 1]);
            const short8 a1 = *reinterpret_cast<const short8*>(&h1_s[bb1 >> 1]);
#pragma unroll
            for (int n = 0; n < 3; ++n) {
                const int tile = wv * 3 + n;
                const short8 b = *reinterpret_cast<const short8*>(
                    &Wf2b[(((kt * 24) + tile) * 64 + lane) * 8]);
                acc[0][n] = __builtin_amdgcn_mfma_f32_16x16x32_bf16(
                    a0, b, acc[0][n], 0, 0, 0);
                acc[1][n] = __builtin_amdgcn_mfma_f32_16x16x32_bf16(
                    a1, b, acc[1][n], 0, 0, 0);
            }
        }

        // epilogue: + bf2, * cutoff -> f_pack[row][c&127][c>>7]
#pragma unroll
        for (int n = 0; n < 3; ++n) {
            const int c  = (wv * 3 + n) * 16 + lr;
            const int cc = c & 127, p = c >> 7;
            const float bb = bf2[c];
#pragma unroll
            for (int m = 0; m < 2; ++m) {
#pragma unroll
                for (int r = 0; r < 4; ++r) {
                    const int row = m * 16 + lh * 4 + r;
                    f_pack[(row * 128 + cc) * 4 + p] =
                        f2b((acc[m][n][r] + bb) * cut_s[row]);
                }
            }
        }
    }
    __syncthreads();

    // ---- message phase: 128 channels x 4 subtiles of 8 sorted edges ----
    {
        const int c   = t & 127;
        const int sub = t >> 7;                 // 0..3
        const ushort4* xp4 = (const ushort4*)x_pack;
        const ushort4* fp4 = (const ushort4*)f_pack;

        float aq = 0.f, a0 = 0.f, a1 = 0.f, a2 = 0.f;
        int cur = tgt_s[sub * 8];
        for (int i = sub * 8; i < sub * 8 + 8; ++i) {
            const int tg = tgt_s[i];
            if (tg != cur) {                    // subtile-uniform branch
                atomicAdd(&out_q[cur * HIDDEN + c], aq);
                atomicAdd(&out_mu[(cur * 3 + 0) * HIDDEN + c], a0);
                atomicAdd(&out_mu[(cur * 3 + 1) * HIDDEN + c], a1);
                atomicAdd(&out_mu[(cur * 3 + 2) * HIDDEN + c], a2);
                aq = a0 = a1 = a2 = 0.f;
                cur = tg;
            }
            const int src = src_s[i];
            const ushort4 xp = xp4[(size_t)src * 128 + c];
            const ushort4 fp = fp4[i * 128 + c];
            const float xrr = b2f(xp.y) * b2f(fp.y);
            const float xmm = b2f(xp.z) * b2f(fp.z);
            aq = fmaf(b2f(xp.x), b2f(fp.x), aq);
            a0 = fmaf(uv_s[i][0], xrr,
                      fmaf(mu[(src * 3 + 0) * HIDDEN + c], xmm, a0));
            a1 = fmaf(uv_s[i][1], xrr,
                      fmaf(mu[(src * 3 + 1) * HIDDEN + c], xmm, a1));
            a2 = fmaf(uv_s[i][2], xrr,
                      fmaf(mu[(src * 3 + 2) * HIDDEN + c], xmm, a2));
        }
        atomicAdd(&out_q[cur * HIDDEN + c], aq);
        atomicAdd(&out_mu[(cur * 3 + 0) * HIDDEN + c], a0);
        atomicAdd(&out_mu[(cur * 3 + 1) * HIDDEN + c], a1);
        atomicAdd(&out_mu[(cur * 3 + 2) * HIDDEN + c], a2);
    }
}

// ---------------------------------------------------------------------------
extern "C" void kernel_launch(void* const* d_in, const int* in_sizes, int n_in,
                              void* d_out, int out_size, void* d_ws, size_t ws_size,
                              hipStream_t stream) {
    const float* q   = (const float*)d_in[0];
    const float* mu  = (const float*)d_in[1];
    const int*   ei  = (const int*)  d_in[2];
    const float* rbf = (const float*)d_in[3];
    const float* uv  = (const float*)d_in[4];
    const float* cut = (const float*)d_in[5];
    const float* W1  = (const float*)d_in[6];
    const float* b1  = (const float*)d_in[7];
    const float* W2  = (const float*)d_in[8];
    const float* b2  = (const float*)d_in[9];
    const float* Wf1 = (const float*)d_in[10];
    const float* bf1 = (const float*)d_in[11];
    const float* Wf2 = (const float*)d_in[12];
    const float* bf2 = (const float*)d_in[13];

    float* out    = (float*)d_out;
    float* out_q  = out;
    float* out_mu = out + N_NODES * HIDDEN;

    // ws layout (bytes), total ~12.1 MB
    char* ws = (char*)d_ws;
    size_t off = 0;
    ushort* Wf2b   = (ushort*)(ws + off); off += 98304;            // 128x384 bf16
    ushort* W1b    = (ushort*)(ws + off); off += 98304;            // 128x384 bf16
    ushort* W2b    = (ushort*)(ws + off); off += 294912;           // 384x384 bf16
    int*    perm   = (int*)   (ws + off); off += (size_t)N_EDGES * 4;
    int*    counts = (int*)   (ws + off); off += (size_t)N_NODES * 4 + 960;
    int*    cursor = (int*)   (ws + off); off += (size_t)N_NODES * 4 + 960;
    ushort* x_pack = (ushort*)(ws + off); off += (size_t)N_NODES * 128 * 4 * 2;
    const bool ws_ok = (off <= ws_size);   // constant across calls

    copy_init_kernel<<<1280, 256, 0, stream>>>(
        (const float4*)q, (const float4*)mu, (float4*)d_out);

    w_prep_kernel<<<(HIDDEN * H3 + 255) / 256, 256, 0, stream>>>(Wf2, Wf2b, HIDDEN);
    w_prep_kernel<<<(HIDDEN * H3 + 255) / 256, 256, 0, stream>>>(W1, W1b, HIDDEN);
    w_prep_kernel<<<(H3 * H3 + 255) / 256, 256, 0, stream>>>(W2, W2b, H3);

    if (ws_ok) {
        zero_counts_kernel<<<(N_NODES + 255) / 256, 256, 0, stream>>>(counts);
        hist_kernel<<<(N_EDGES + 255) / 256, 256, 0, stream>>>(ei, counts);
        scan_kernel<<<1, SCAN_NT, 0, stream>>>(counts, cursor);
        scatter_kernel<<<(N_EDGES + 255) / 256, 256, 0, stream>>>(ei, cursor, perm);
    } else {
        iota_kernel<<<(N_EDGES + 255) / 256, 256, 0, stream>>>(perm);
    }

    node_mlp_kernel<<<(N_NODES + 31) / 32, 512, 0, stream>>>(
        q, W1b, b1, W2b, b2, x_pack);

    edge_kernel<<<N_EDGES / 32, 512, 0, stream>>>(
        x_pack, mu, ei, perm, rbf, uv, cut, Wf1, bf1, Wf2b, bf2, out_q, out_mu);
}

// Round 6
// 339.336 us; speedup vs baseline: 5.7531x; 1.0825x over previous
//
#include <hip/hip_runtime.h>
#include <math.h>

#define N_NODES 10000
#define N_EDGES 320000
#define HIDDEN  128
#define NUM_RBF 20
#define H3      384   // 3*HIDDEN
#define FP_STRIDE 516 // f_pack row stride in ushorts (1032B): lh-rows -> distinct banks

typedef __attribute__((ext_vector_type(8))) short short8;
typedef __attribute__((ext_vector_type(8))) unsigned short ushort8v;
typedef __attribute__((ext_vector_type(4))) float floatx4;

__device__ __forceinline__ float b2f(ushort u) {
    unsigned v = ((unsigned)u) << 16; float f; __builtin_memcpy(&f, &v, 4); return f;
}
__device__ __forceinline__ ushort f2b(float f) {   // RNE f32 -> bf16
    unsigned x; __builtin_memcpy(&x, &f, 4);
    return (ushort)((x + 0x7fffu + ((x >> 16) & 1u)) >> 16);
}

// ---------------------------------------------------------------------------
// Kernel A (fused prep): grid-split over independent jobs.
//   seg0: out[0:NQ)  = q                  (1250 blocks, float4)
//   seg1: out[NQ:..) = mu                 (3750 blocks, float4)
//   seg2: src_pack[n][c].slot1 = bf16 mu  (5000 blocks, ushort4 store)
//   seg3: w_prep Wf2 / W1 / W2            (960 blocks)
//   seg4: zero counts                     (40 blocks)
// ---------------------------------------------------------------------------
#define A_Q  1250
#define A_MU 3750
#define A_PK 5000
#define A_W  960
#define A_Z  40

__device__ __forceinline__ void w_prep_one(const float* __restrict__ W,
                                           ushort* __restrict__ Wb, int idx) {
    const int k = idx / H3, j = idx % H3;
    const int kt = k >> 5, r = k & 31;
    const int hi = r >> 3, b = r & 7;
    const int nt = j >> 4, jj = j & 15;
    const int lane = hi * 16 + jj;
    Wb[(((kt * 24 + nt) * 64) + lane) * 8 + b] = f2b(W[k * H3 + j]);
}

__global__ __launch_bounds__(256) void prep_kernel(
    const float4* __restrict__ q4, const float4* __restrict__ mu4,
    const float* __restrict__ mu,
    const float* __restrict__ Wf2, const float* __restrict__ W1,
    const float* __restrict__ W2,
    float4* __restrict__ out4, ushort4* __restrict__ src_pack,
    ushort* __restrict__ Wf2b, ushort* __restrict__ W1b,
    ushort* __restrict__ W2b, int* __restrict__ counts) {

    const int b = blockIdx.x, t = threadIdx.x;
    if (b < A_Q) {
        const int i = b * 256 + t;
        if (i < N_NODES * HIDDEN / 4) out4[i] = q4[i];
    } else if (b < A_Q + A_MU) {
        const int i = (b - A_Q) * 256 + t;
        if (i < N_NODES * 3 * HIDDEN / 4)
            out4[N_NODES * HIDDEN / 4 + i] = mu4[i];
    } else if (b < A_Q + A_MU + A_PK) {
        const int i = (b - A_Q - A_MU) * 256 + t;   // over N*128
        if (i < N_NODES * HIDDEN) {
            const int n = i >> 7, c = i & 127;
            ushort4 v;
            v.x = f2b(mu[(n * 3 + 0) * HIDDEN + c]);
            v.y = f2b(mu[(n * 3 + 1) * HIDDEN + c]);
            v.z = f2b(mu[(n * 3 + 2) * HIDDEN + c]);
            v.w = 0;
            src_pack[(size_t)i * 2 + 1] = v;        // slot 1 of 16B record
        }
    } else if (b < A_Q + A_MU + A_PK + A_W) {
        const int i = (b - A_Q - A_MU - A_PK) * 256 + t;  // over 245760
        if (i < 49152) w_prep_one(Wf2, Wf2b, i);
        else if (i < 98304) w_prep_one(W1, W1b, i - 49152);
        else if (i < 245760) w_prep_one(W2, W2b, i - 98304);
    } else {
        const int i = (b - A_Q - A_MU - A_PK - A_W) * 256 + t;
        if (i < N_NODES) counts[i] = 0;
    }
}

// ---------------------------------------------------------------------------
// Kernel B: histogram of targets
// ---------------------------------------------------------------------------
__global__ void hist_kernel(const int* __restrict__ ei, int* __restrict__ counts) {
    const int i = blockIdx.x * blockDim.x + threadIdx.x;
    if (i < N_EDGES) atomicAdd(&counts[ei[i]], 1);   // row 0 = target
}

// ---------------------------------------------------------------------------
// Kernel C: single-block exclusive scan -> cursor
// ---------------------------------------------------------------------------
#define SCAN_NT 1024
#define SCAN_CHUNK 10
__global__ __launch_bounds__(SCAN_NT) void scan_kernel(
    const int* __restrict__ counts, int* __restrict__ cursor) {
    __shared__ int s[SCAN_NT];
    const int t = threadIdx.x;
    const int base = t * SCAN_CHUNK;
    int local[SCAN_CHUNK];
    int sum = 0;
#pragma unroll
    for (int i = 0; i < SCAN_CHUNK; ++i) {
        const int idx = base + i;
        const int v = (idx < N_NODES) ? counts[idx] : 0;
        local[i] = sum;
        sum += v;
    }
    s[t] = sum;
    __syncthreads();
    for (int d = 1; d < SCAN_NT; d <<= 1) {
        const int v = (t >= d) ? s[t - d] : 0;
        __syncthreads();
        s[t] += v;
        __syncthreads();
    }
    const int excl = (t == 0) ? 0 : s[t - 1];
#pragma unroll
    for (int i = 0; i < SCAN_CHUNK; ++i) {
        const int idx = base + i;
        if (idx < N_NODES) cursor[idx] = excl + local[i];
    }
}

// identity perm fallback (ws too small for CSR build)
__global__ void iota_kernel(int* __restrict__ perm) {
    const int i = blockIdx.x * blockDim.x + threadIdx.x;
    if (i < N_EDGES) perm[i] = i;
}

// ---------------------------------------------------------------------------
// Kernel D (fused): blocks [0,313) node MLP (MFMA); [313,938) perm scatter.
// 512 threads.
// ---------------------------------------------------------------------------
#define D_NODE 313
#define D_SCAT 625

__global__ __launch_bounds__(512) void node_scatter_kernel(
    const float*  __restrict__ q,
    const ushort* __restrict__ W1b, const float* __restrict__ b1,
    const ushort* __restrict__ W2b, const float* __restrict__ b2,
    const int* __restrict__ ei, int* __restrict__ cursor,
    int* __restrict__ perm,
    ushort* __restrict__ x_pack) {          // = src_pack as ushorts

    __shared__ ushort q_s[32 * HIDDEN];   // 8 KB, 256B rows, XOR-swizzled
    __shared__ ushort h_s[32 * H3];       // 24 KB, 768B rows, XOR-swizzled

    const int t = threadIdx.x;

    if (blockIdx.x >= D_NODE) {           // ---- scatter branch ----
        const int i = (blockIdx.x - D_NODE) * 512 + t;
        if (i < N_EDGES) {
            const int tg = ei[i];
            const int pos = atomicAdd(&cursor[tg], 1);
            perm[pos] = i;
        }
        return;
    }

    // ---- node MLP branch ----
    const int n0 = blockIdx.x * 32;
    const int nt = min(32, N_NODES - n0);

    for (int idx = t; idx < 32 * HIDDEN; idx += 512) {
        const int i = idx >> 7, k = idx & 127;
        const float v = (i < nt) ? q[(n0 + i) * HIDDEN + k] : 0.0f;
        const int byte = i * 256 + (((k << 1)) ^ ((i & 7) << 4));
        q_s[byte >> 1] = f2b(v);
    }
    __syncthreads();

    const int wv = t >> 6, lane = t & 63;
    const int lr = lane & 15, lh = lane >> 4;

    // layer 1: [32,128] @ [128,384] -> silu -> h_s
    {
        floatx4 acc[2][3];
#pragma unroll
        for (int m = 0; m < 2; ++m)
#pragma unroll
            for (int n = 0; n < 3; ++n) acc[m][n] = (floatx4){0.f, 0.f, 0.f, 0.f};

#pragma unroll
        for (int kt = 0; kt < 4; ++kt) {
            const int kbyte = kt * 64 + lh * 16;
            const int r0 = lr, r1 = 16 + lr;
            const int b0 = r0 * 256 + (kbyte ^ ((r0 & 7) << 4));
            const int bb1 = r1 * 256 + (kbyte ^ ((r1 & 7) << 4));
            const short8 a0 = *reinterpret_cast<const short8*>(&q_s[b0 >> 1]);
            const short8 a1 = *reinterpret_cast<const short8*>(&q_s[bb1 >> 1]);
#pragma unroll
            for (int n = 0; n < 3; ++n) {
                const int tile = wv * 3 + n;
                const short8 b = *reinterpret_cast<const short8*>(
                    &W1b[(((kt * 24) + tile) * 64 + lane) * 8]);
                acc[0][n] = __builtin_amdgcn_mfma_f32_16x16x32_bf16(
                    a0, b, acc[0][n], 0, 0, 0);
                acc[1][n] = __builtin_amdgcn_mfma_f32_16x16x32_bf16(
                    a1, b, acc[1][n], 0, 0, 0);
            }
        }
#pragma unroll
        for (int n = 0; n < 3; ++n) {
            const int c = (wv * 3 + n) * 16 + lr;
            const float bb = b1[c];
#pragma unroll
            for (int m = 0; m < 2; ++m) {
#pragma unroll
                for (int r = 0; r < 4; ++r) {
                    const int row = m * 16 + lh * 4 + r;
                    const float v = acc[m][n][r] + bb;
                    const float s = v / (1.0f + __expf(-v));
                    const int byte = row * 768 + (((c << 1)) ^ ((row & 7) << 4));
                    h_s[byte >> 1] = f2b(s);
                }
            }
        }
    }
    __syncthreads();

    // layer 2: [32,384] @ [384,384] -> x slots of src_pack
    {
        floatx4 acc[2][3];
#pragma unroll
        for (int m = 0; m < 2; ++m)
#pragma unroll
            for (int n = 0; n < 3; ++n) acc[m][n] = (floatx4){0.f, 0.f, 0.f, 0.f};

#pragma unroll
        for (int kt = 0; kt < 12; ++kt) {
            const int kbyte = kt * 64 + lh * 16;
            const int r0 = lr, r1 = 16 + lr;
            const int b0 = r0 * 768 + (kbyte ^ ((r0 & 7) << 4));
            const int bb1 = r1 * 768 + (kbyte ^ ((r1 & 7) << 4));
            const short8 a0 = *reinterpret_cast<const short8*>(&h_s[b0 >> 1]);
            const short8 a1 = *reinterpret_cast<const short8*>(&h_s[bb1 >> 1]);
#pragma unroll
            for (int n = 0; n < 3; ++n) {
                const int tile = wv * 3 + n;
                const short8 b = *reinterpret_cast<const short8*>(
                    &W2b[(((kt * 24) + tile) * 64 + lane) * 8]);
                acc[0][n] = __builtin_amdgcn_mfma_f32_16x16x32_bf16(
                    a0, b, acc[0][n], 0, 0, 0);
                acc[1][n] = __builtin_amdgcn_mfma_f32_16x16x32_bf16(
                    a1, b, acc[1][n], 0, 0, 0);
            }
        }
#pragma unroll
        for (int n = 0; n < 3; ++n) {
            const int c  = (wv * 3 + n) * 16 + lr;
            const int cc = c & 127, p = c >> 7;          // p=0:xq 1:xr 2:xm
            const float bb = b2[c];
#pragma unroll
            for (int m = 0; m < 2; ++m) {
#pragma unroll
                for (int r = 0; r < 4; ++r) {
                    const int row = m * 16 + lh * 4 + r;
                    if (row < nt)
                        x_pack[((size_t)(n0 + row) * 128 + cc) * 8 + p] =
                            f2b(acc[m][n][r] + bb);
                }
            }
        }
    }
}

// ---------------------------------------------------------------------------
// Kernel E: fused edge filter MLP (MFMA) + sorted segment reduction.
// 512 threads; message phase = 128 channels x 4 subtiles of 8 edges.
// ---------------------------------------------------------------------------
__global__ __launch_bounds__(512) void edge_kernel(
    const ushort* __restrict__ src_pack,  // [N][128][8] bf16 (xq,xr,xm,_,m0,m1,m2,_)
    const int*    __restrict__ ei,
    const int*    __restrict__ perm,
    const float*  __restrict__ rbf,
    const float*  __restrict__ uv,
    const float*  __restrict__ cut,
    const float*  __restrict__ Wf1, const float* __restrict__ bf1,
    const ushort* __restrict__ Wf2b,
    const float*  __restrict__ bf2,
    float* __restrict__ out_q,            // [N,128]   pre-init to q
    float* __restrict__ out_mu) {         // [N,3,128] pre-init to mu

    __shared__ float  rbf_s[32][NUM_RBF];       // 2.5 KB
    __shared__ ushort h1_s[32 * HIDDEN];        // 8 KB, XOR-swizzled
    __shared__ ushort f_pack[32 * FP_STRIDE];   // 33 KB: row stride 1032B
    __shared__ int    eid_s[32], src_s[32], tgt_s[32];
    __shared__ float  uv_s[32][3], cut_s[32];

    const int e0 = blockIdx.x * 32;
    const int t  = threadIdx.x;

    if (t < 32) {
        const int eid = perm[e0 + t];
        eid_s[t] = eid;
        tgt_s[t] = ei[eid];
        src_s[t] = ei[N_EDGES + eid];
        cut_s[t] = cut[eid];
        uv_s[t][0] = uv[eid * 3 + 0];
        uv_s[t][1] = uv[eid * 3 + 1];
        uv_s[t][2] = uv[eid * 3 + 2];
    }
    __syncthreads();
    for (int idx = t; idx < 32 * NUM_RBF; idx += 512) {
        const int i = idx / NUM_RBF, k = idx % NUM_RBF;
        rbf_s[i][k] = rbf[eid_s[i] * NUM_RBF + k];
    }
    __syncthreads();

    // filter layer 1 (f32 VALU) -> bf16 swizzled LDS
    {
        const int col = t & 127;
        const int grp = t >> 7;
        const float bb = bf1[col];
        for (int i = grp; i < 32; i += 4) {
            float acc = bb;
#pragma unroll
            for (int k = 0; k < NUM_RBF; ++k)
                acc = fmaf(rbf_s[i][k], Wf1[k * HIDDEN + col], acc);
            const float h = acc / (1.0f + __expf(-acc));
            const int byte = i * 256 + (((col << 1)) ^ ((i & 7) << 4));
            h1_s[byte >> 1] = f2b(h);
        }
    }
    __syncthreads();

    // filter layer 2 via MFMA -> f_pack (bank-spread rows)
    {
        const int wv   = t >> 6;
        const int lane = t & 63;
        const int lr   = lane & 15;
        const int lh   = lane >> 4;

        floatx4 acc[2][3];
#pragma unroll
        for (int m = 0; m < 2; ++m)
#pragma unroll
            for (int n = 0; n < 3; ++n) acc[m][n] = (floatx4){0.f, 0.f, 0.f, 0.f};

#pragma unroll
        for (int kt = 0; kt < 4; ++kt) {
            const int kbyte = kt * 64 + lh * 16;
            const int r0 = lr, r1 = 16 + lr;
            const int b0 = r0 * 256 + (kbyte ^ ((r0 & 7) << 4));
            const int bb1 = r1 * 256 + (kbyte ^ ((r1 & 7) << 4));
            const short8 a0 = *reinterpret_cast<const short8*>(&h1_s[b0 >> 1]);
            const short8 a1 = *reinterpret_cast<const short8*>(&h1_s[bb1 >> 1]);
#pragma unroll
            for (int n = 0; n < 3; ++n) {
                const int tile = wv * 3 + n;
                const short8 b = *reinterpret_cast<const short8*>(
                    &Wf2b[(((kt * 24) + tile) * 64 + lane) * 8]);
                acc[0][n] = __builtin_amdgcn_mfma_f32_16x16x32_bf16(
                    a0, b, acc[0][n], 0, 0, 0);
                acc[1][n] = __builtin_amdgcn_mfma_f32_16x16x32_bf16(
                    a1, b, acc[1][n], 0, 0, 0);
            }
        }

#pragma unroll
        for (int n = 0; n < 3; ++n) {
            const int c  = (wv * 3 + n) * 16 + lr;
            const int cc = c & 127, p = c >> 7;
            const float bb = bf2[c];
#pragma unroll
            for (int m = 0; m < 2; ++m) {
#pragma unroll
                for (int r = 0; r < 4; ++r) {
                    const int row = m * 16 + lh * 4 + r;
                    f_pack[row * FP_STRIDE + cc * 4 + p] =
                        f2b((acc[m][n][r] + bb) * cut_s[row]);
                }
            }
        }
    }
    __syncthreads();

    // message phase: 128 channels x 4 subtiles of 8 sorted edges
    {
        const int c   = t & 127;
        const int sub = t >> 7;
        const ushort8v* sp8 = (const ushort8v*)src_pack;

        float aq = 0.f, a0 = 0.f, a1 = 0.f, a2 = 0.f;
        int cur = tgt_s[sub * 8];
        for (int i = sub * 8; i < sub * 8 + 8; ++i) {
            const int tg = tgt_s[i];
            if (tg != cur) {                    // subtile-uniform branch
                atomicAdd(&out_q[cur * HIDDEN + c], aq);
                atomicAdd(&out_mu[(cur * 3 + 0) * HIDDEN + c], a0);
                atomicAdd(&out_mu[(cur * 3 + 1) * HIDDEN + c], a1);
                atomicAdd(&out_mu[(cur * 3 + 2) * HIDDEN + c], a2);
                aq = a0 = a1 = a2 = 0.f;
                cur = tg;
            }
            const int src = src_s[i];
            const ushort8v sp = sp8[(size_t)src * 128 + c];
            const ushort4  fp = *reinterpret_cast<const ushort4*>(
                &f_pack[i * FP_STRIDE + c * 4]);
            const float xrr = b2f(sp[1]) * b2f(fp.y);
            const float xmm = b2f(sp[2]) * b2f(fp.z);
            aq = fmaf(b2f(sp[0]), b2f(fp.x), aq);
            a0 = fmaf(uv_s[i][0], xrr, fmaf(b2f(sp[4]), xmm, a0));
            a1 = fmaf(uv_s[i][1], xrr, fmaf(b2f(sp[5]), xmm, a1));
            a2 = fmaf(uv_s[i][2], xrr, fmaf(b2f(sp[6]), xmm, a2));
        }
        atomicAdd(&out_q[cur * HIDDEN + c], aq);
        atomicAdd(&out_mu[(cur * 3 + 0) * HIDDEN + c], a0);
        atomicAdd(&out_mu[(cur * 3 + 1) * HIDDEN + c], a1);
        atomicAdd(&out_mu[(cur * 3 + 2) * HIDDEN + c], a2);
    }
}

// ---------------------------------------------------------------------------
extern "C" void kernel_launch(void* const* d_in, const int* in_sizes, int n_in,
                              void* d_out, int out_size, void* d_ws, size_t ws_size,
                              hipStream_t stream) {
    const float* q   = (const float*)d_in[0];
    const float* mu  = (const float*)d_in[1];
    const int*   ei  = (const int*)  d_in[2];
    const float* rbf = (const float*)d_in[3];
    const float* uv  = (const float*)d_in[4];
    const float* cut = (const float*)d_in[5];
    const float* W1  = (const float*)d_in[6];
    const float* b1  = (const float*)d_in[7];
    const float* W2  = (const float*)d_in[8];
    const float* b2  = (const float*)d_in[9];
    const float* Wf1 = (const float*)d_in[10];
    const float* bf1 = (const float*)d_in[11];
    const float* Wf2 = (const float*)d_in[12];
    const float* bf2 = (const float*)d_in[13];

    float* out    = (float*)d_out;
    float* out_q  = out;
    float* out_mu = out + N_NODES * HIDDEN;

    // ws layout (bytes), total ~22.3 MB
    char* ws = (char*)d_ws;
    size_t off = 0;
    ushort* Wf2b     = (ushort*)(ws + off); off += 98304;
    ushort* W1b      = (ushort*)(ws + off); off += 98304;
    ushort* W2b      = (ushort*)(ws + off); off += 294912;
    ushort* src_pack = (ushort*)(ws + off); off += (size_t)N_NODES * 128 * 8 * 2;
    int*    perm     = (int*)   (ws + off); off += (size_t)N_EDGES * 4;
    int*    counts   = (int*)   (ws + off); off += (size_t)N_NODES * 4 + 960;
    int*    cursor   = (int*)   (ws + off); off += (size_t)N_NODES * 4 + 960;
    const bool ws_ok = (off <= ws_size);   // constant across calls

    // A: fused prep
    prep_kernel<<<A_Q + A_MU + A_PK + A_W + A_Z, 256, 0, stream>>>(
        (const float4*)q, (const float4*)mu, mu, Wf2, W1, W2,
        (float4*)d_out, (ushort4*)src_pack, Wf2b, W1b, W2b, counts);

    if (ws_ok) {
        hist_kernel<<<(N_EDGES + 255) / 256, 256, 0, stream>>>(ei, counts);
        scan_kernel<<<1, SCAN_NT, 0, stream>>>(counts, cursor);
    } else {
        iota_kernel<<<(N_EDGES + 255) / 256, 256, 0, stream>>>(perm);
    }

    // D: node MLP (+ scatter when sorting)
    node_scatter_kernel<<<ws_ok ? (D_NODE + D_SCAT) : D_NODE, 512, 0, stream>>>(
        q, W1b, b1, W2b, b2, ei, cursor, perm, src_pack);

    edge_kernel<<<N_EDGES / 32, 512, 0, stream>>>(
        src_pack, ei, perm, rbf, uv, cut, Wf1, bf1, Wf2b, bf2, out_q, out_mu);
}

// Round 7
// 325.490 us; speedup vs baseline: 5.9978x; 1.0425x over previous
//
#include <hip/hip_runtime.h>
#include <math.h>

#define N_NODES 10000
#define N_EDGES 320000
#define HIDDEN  128
#define NUM_RBF 20
#define H3      384   // 3*HIDDEN
#define FP_STRIDE 516 // f_pack row stride in ushorts (1032B)
#define RBF_STRIDE 40 // rbf_s row stride in ushorts (80B): 2-way banks on A-frag read

typedef __attribute__((ext_vector_type(8))) short short8;
typedef __attribute__((ext_vector_type(8))) unsigned short ushort8v;
typedef __attribute__((ext_vector_type(4))) float floatx4;

__device__ __forceinline__ float b2f(ushort u) {
    unsigned v = ((unsigned)u) << 16; float f; __builtin_memcpy(&f, &v, 4); return f;
}
__device__ __forceinline__ ushort f2b(float f) {   // RNE f32 -> bf16
    unsigned x; __builtin_memcpy(&x, &f, 4);
    return (ushort)((x + 0x7fffu + ((x >> 16) & 1u)) >> 16);
}

// ---------------------------------------------------------------------------
// Kernel A (fused prep), grid-split:
//   seg0: out[0:NQ)  = q                    (1250 blocks)
//   seg1: out[NQ:..) = mu                   (3750 blocks)
//   seg2: src_pack mu slots (bf16)          (5000 blocks)
//   seg3: w_prep Wf2/W1/W2 + Wf1b(bias-fold)(976 blocks)
//   seg4: histogram of targets              (1250 blocks; counts pre-memset)
// ---------------------------------------------------------------------------
#define A_Q  1250
#define A_MU 3750
#define A_PK 5000
#define A_W  976
#define A_H  1250

__device__ __forceinline__ void w_prep_one(const float* __restrict__ W,
                                           ushort* __restrict__ Wb, int idx) {
    const int k = idx / H3, j = idx % H3;
    const int kt = k >> 5, r = k & 31;
    const int hi = r >> 3, b = r & 7;
    const int nt = j >> 4, jj = j & 15;
    const int lane = hi * 16 + jj;
    Wb[(((kt * 24 + nt) * 64) + lane) * 8 + b] = f2b(W[k * H3 + j]);
}

__global__ __launch_bounds__(256) void prep_kernel(
    const float4* __restrict__ q4, const float4* __restrict__ mu4,
    const float* __restrict__ mu,
    const float* __restrict__ Wf2, const float* __restrict__ W1,
    const float* __restrict__ W2,
    const float* __restrict__ Wf1, const float* __restrict__ bf1,
    const int* __restrict__ ei,
    float4* __restrict__ out4, ushort4* __restrict__ src_pack,
    ushort* __restrict__ Wf2b, ushort* __restrict__ W1b,
    ushort* __restrict__ W2b, ushort* __restrict__ Wf1b,
    int* __restrict__ counts, int do_hist) {

    const int b = blockIdx.x, t = threadIdx.x;
    if (b < A_Q) {
        const int i = b * 256 + t;
        if (i < N_NODES * HIDDEN / 4) out4[i] = q4[i];
    } else if (b < A_Q + A_MU) {
        const int i = (b - A_Q) * 256 + t;
        if (i < N_NODES * 3 * HIDDEN / 4)
            out4[N_NODES * HIDDEN / 4 + i] = mu4[i];
    } else if (b < A_Q + A_MU + A_PK) {
        const int i = (b - A_Q - A_MU) * 256 + t;   // over N*128
        if (i < N_NODES * HIDDEN) {
            const int n = i >> 7, c = i & 127;
            ushort4 v;
            v.x = f2b(mu[(n * 3 + 0) * HIDDEN + c]);
            v.y = f2b(mu[(n * 3 + 1) * HIDDEN + c]);
            v.z = f2b(mu[(n * 3 + 2) * HIDDEN + c]);
            v.w = 0;
            src_pack[(size_t)i * 2 + 1] = v;        // slot 1 of 16B record
        }
    } else if (b < A_Q + A_MU + A_PK + A_W) {
        const int i = (b - A_Q - A_MU - A_PK) * 256 + t;  // over 249856
        if (i < 49152) w_prep_one(Wf2, Wf2b, i);
        else if (i < 98304) w_prep_one(W1, W1b, i - 49152);
        else if (i < 245760) w_prep_one(W2, W2b, i - 98304);
        else {
            // Wf1b: [K=32 pad][128], row 20 = bias, rows 21..31 = 0
            const int idx = i - 245760;             // over 4096
            const int k = idx >> 7, c = idx & 127;
            const float v = (k < NUM_RBF) ? Wf1[k * HIDDEN + c]
                          : (k == NUM_RBF ? bf1[c] : 0.0f);
            const int nt = c >> 4, lr = c & 15;
            const int lh = k >> 3, bb = k & 7;
            Wf1b[((nt * 64) + lh * 16 + lr) * 8 + bb] = f2b(v);
        }
    } else {
        if (!do_hist) return;
        const int i = (b - A_Q - A_MU - A_PK - A_W) * 256 + t;
        if (i < N_EDGES) atomicAdd(&counts[ei[i]], 1);  // row 0 = target
    }
}

// ---------------------------------------------------------------------------
// Kernel C: single-block exclusive scan -> cursor
// ---------------------------------------------------------------------------
#define SCAN_NT 1024
#define SCAN_CHUNK 10
__global__ __launch_bounds__(SCAN_NT) void scan_kernel(
    const int* __restrict__ counts, int* __restrict__ cursor) {
    __shared__ int s[SCAN_NT];
    const int t = threadIdx.x;
    const int base = t * SCAN_CHUNK;
    int local[SCAN_CHUNK];
    int sum = 0;
#pragma unroll
    for (int i = 0; i < SCAN_CHUNK; ++i) {
        const int idx = base + i;
        const int v = (idx < N_NODES) ? counts[idx] : 0;
        local[i] = sum;
        sum += v;
    }
    s[t] = sum;
    __syncthreads();
    for (int d = 1; d < SCAN_NT; d <<= 1) {
        const int v = (t >= d) ? s[t - d] : 0;
        __syncthreads();
        s[t] += v;
        __syncthreads();
    }
    const int excl = (t == 0) ? 0 : s[t - 1];
#pragma unroll
    for (int i = 0; i < SCAN_CHUNK; ++i) {
        const int idx = base + i;
        if (idx < N_NODES) cursor[idx] = excl + local[i];
    }
}

// identity perm fallback (ws too small for CSR build)
__global__ void iota_kernel(int* __restrict__ perm) {
    const int i = blockIdx.x * blockDim.x + threadIdx.x;
    if (i < N_EDGES) perm[i] = i;
}

// ---------------------------------------------------------------------------
// Kernel D (fused): blocks [0,313) node MLP (MFMA); [313,938) perm scatter.
// ---------------------------------------------------------------------------
#define D_NODE 313
#define D_SCAT 625

__global__ __launch_bounds__(512) void node_scatter_kernel(
    const float*  __restrict__ q,
    const ushort* __restrict__ W1b, const float* __restrict__ b1,
    const ushort* __restrict__ W2b, const float* __restrict__ b2,
    const int* __restrict__ ei, int* __restrict__ cursor,
    int* __restrict__ perm,
    ushort* __restrict__ x_pack) {          // = src_pack as ushorts

    __shared__ ushort q_s[32 * HIDDEN];   // 8 KB, 256B rows, XOR-swizzled
    __shared__ ushort h_s[32 * H3];       // 24 KB, 768B rows, XOR-swizzled

    const int t = threadIdx.x;

    if (blockIdx.x >= D_NODE) {           // ---- scatter branch ----
        const int i = (blockIdx.x - D_NODE) * 512 + t;
        if (i < N_EDGES) {
            const int tg = ei[i];
            const int pos = atomicAdd(&cursor[tg], 1);
            perm[pos] = i;
        }
        return;
    }

    // ---- node MLP branch ----
    const int n0 = blockIdx.x * 32;
    const int nt = min(32, N_NODES - n0);

    for (int idx = t; idx < 32 * HIDDEN; idx += 512) {
        const int i = idx >> 7, k = idx & 127;
        const float v = (i < nt) ? q[(n0 + i) * HIDDEN + k] : 0.0f;
        const int byte = i * 256 + (((k << 1)) ^ ((i & 7) << 4));
        q_s[byte >> 1] = f2b(v);
    }
    __syncthreads();

    const int wv = t >> 6, lane = t & 63;
    const int lr = lane & 15, lh = lane >> 4;

    // layer 1: [32,128] @ [128,384] -> silu -> h_s
    {
        floatx4 acc[2][3];
#pragma unroll
        for (int m = 0; m < 2; ++m)
#pragma unroll
            for (int n = 0; n < 3; ++n) acc[m][n] = (floatx4){0.f, 0.f, 0.f, 0.f};

#pragma unroll
        for (int kt = 0; kt < 4; ++kt) {
            const int kbyte = kt * 64 + lh * 16;
            const int r0 = lr, r1 = 16 + lr;
            const int b0 = r0 * 256 + (kbyte ^ ((r0 & 7) << 4));
            const int bb1 = r1 * 256 + (kbyte ^ ((r1 & 7) << 4));
            const short8 a0 = *reinterpret_cast<const short8*>(&q_s[b0 >> 1]);
            const short8 a1 = *reinterpret_cast<const short8*>(&q_s[bb1 >> 1]);
#pragma unroll
            for (int n = 0; n < 3; ++n) {
                const int tile = wv * 3 + n;
                const short8 b = *reinterpret_cast<const short8*>(
                    &W1b[(((kt * 24) + tile) * 64 + lane) * 8]);
                acc[0][n] = __builtin_amdgcn_mfma_f32_16x16x32_bf16(
                    a0, b, acc[0][n], 0, 0, 0);
                acc[1][n] = __builtin_amdgcn_mfma_f32_16x16x32_bf16(
                    a1, b, acc[1][n], 0, 0, 0);
            }
        }
#pragma unroll
        for (int n = 0; n < 3; ++n) {
            const int c = (wv * 3 + n) * 16 + lr;
            const float bb = b1[c];
#pragma unroll
            for (int m = 0; m < 2; ++m) {
#pragma unroll
                for (int r = 0; r < 4; ++r) {
                    const int row = m * 16 + lh * 4 + r;
                    const float v = acc[m][n][r] + bb;
                    const float s = v / (1.0f + __expf(-v));
                    const int byte = row * 768 + (((c << 1)) ^ ((row & 7) << 4));
                    h_s[byte >> 1] = f2b(s);
                }
            }
        }
    }
    __syncthreads();

    // layer 2: [32,384] @ [384,384] -> x slots of src_pack
    {
        floatx4 acc[2][3];
#pragma unroll
        for (int m = 0; m < 2; ++m)
#pragma unroll
            for (int n = 0; n < 3; ++n) acc[m][n] = (floatx4){0.f, 0.f, 0.f, 0.f};

#pragma unroll
        for (int kt = 0; kt < 12; ++kt) {
            const int kbyte = kt * 64 + lh * 16;
            const int r0 = lr, r1 = 16 + lr;
            const int b0 = r0 * 768 + (kbyte ^ ((r0 & 7) << 4));
            const int bb1 = r1 * 768 + (kbyte ^ ((r1 & 7) << 4));
            const short8 a0 = *reinterpret_cast<const short8*>(&h_s[b0 >> 1]);
            const short8 a1 = *reinterpret_cast<const short8*>(&h_s[bb1 >> 1]);
#pragma unroll
            for (int n = 0; n < 3; ++n) {
                const int tile = wv * 3 + n;
                const short8 b = *reinterpret_cast<const short8*>(
                    &W2b[(((kt * 24) + tile) * 64 + lane) * 8]);
                acc[0][n] = __builtin_amdgcn_mfma_f32_16x16x32_bf16(
                    a0, b, acc[0][n], 0, 0, 0);
                acc[1][n] = __builtin_amdgcn_mfma_f32_16x16x32_bf16(
                    a1, b, acc[1][n], 0, 0, 0);
            }
        }
#pragma unroll
        for (int n = 0; n < 3; ++n) {
            const int c  = (wv * 3 + n) * 16 + lr;
            const int cc = c & 127, p = c >> 7;          // p=0:xq 1:xr 2:xm
            const float bb = b2[c];
#pragma unroll
            for (int m = 0; m < 2; ++m) {
#pragma unroll
                for (int r = 0; r < 4; ++r) {
                    const int row = m * 16 + lh * 4 + r;
                    if (row < nt)
                        x_pack[((size_t)(n0 + row) * 128 + cc) * 8 + p] =
                            f2b(acc[m][n][r] + bb);
                }
            }
        }
    }
}

// ---------------------------------------------------------------------------
// Kernel E: fused edge filter MLP (full MFMA) + sorted segment reduction.
// 512 threads; message phase = 128 channels x 4 subtiles of 8 edges,
// with explicit 8-deep gather prefetch.
// ---------------------------------------------------------------------------
__global__ __launch_bounds__(512) void edge_kernel(
    const ushort* __restrict__ src_pack,  // [N][128][8] bf16 (xq,xr,xm,_,m0,m1,m2,_)
    const int*    __restrict__ ei,
    const int*    __restrict__ perm,
    const float*  __restrict__ rbf,
    const float*  __restrict__ uv,
    const float*  __restrict__ cut,
    const ushort* __restrict__ Wf1b,      // [32pad][128] frag-linear (bias-folded)
    const ushort* __restrict__ Wf2b,
    const float*  __restrict__ bf2,
    float* __restrict__ out_q,            // [N,128]   pre-init to q
    float* __restrict__ out_mu) {         // [N,3,128] pre-init to mu

    __shared__ ushort rbf_s[32 * RBF_STRIDE];   // 2.5 KB bf16, K padded to 32
    __shared__ ushort h1_s[32 * HIDDEN];        // 8 KB, XOR-swizzled
    __shared__ ushort f_pack[32 * FP_STRIDE];   // 33 KB
    __shared__ int    eid_s[32], src_s[32], tgt_s[32];
    __shared__ float  uv_s[32][3], cut_s[32];

    const int e0 = blockIdx.x * 32;
    const int t  = threadIdx.x;

    if (t < 32) {
        const int eid = perm[e0 + t];
        eid_s[t] = eid;
        tgt_s[t] = ei[eid];
        src_s[t] = ei[N_EDGES + eid];
        cut_s[t] = cut[eid];
        uv_s[t][0] = uv[eid * 3 + 0];
        uv_s[t][1] = uv[eid * 3 + 1];
        uv_s[t][2] = uv[eid * 3 + 2];
    }
    __syncthreads();
    // stage rbf -> bf16 padded (slot NUM_RBF = 1.0 carries the bias row)
    for (int idx = t; idx < 32 * RBF_STRIDE; idx += 512) {
        const int i = idx / RBF_STRIDE, k = idx % RBF_STRIDE;
        const float v = (k < NUM_RBF) ? rbf[eid_s[i] * NUM_RBF + k]
                      : (k == NUM_RBF ? 1.0f : 0.0f);
        rbf_s[idx] = f2b(v);
    }
    __syncthreads();

    const int wv   = t >> 6;
    const int lane = t & 63;
    const int lr   = lane & 15;
    const int lh   = lane >> 4;

    // ---- filter layer 1 via MFMA: [32,32pad] @ [32pad,128] -> silu -> h1_s ----
    {
        floatx4 acc1[2];
        acc1[0] = (floatx4){0.f, 0.f, 0.f, 0.f};
        acc1[1] = (floatx4){0.f, 0.f, 0.f, 0.f};
        const short8 bfrag = *reinterpret_cast<const short8*>(
            &Wf1b[(wv * 64 + lane) * 8]);
#pragma unroll
        for (int m = 0; m < 2; ++m) {
            const short8 a = *reinterpret_cast<const short8*>(
                &rbf_s[(m * 16 + lr) * RBF_STRIDE + lh * 8]);
            acc1[m] = __builtin_amdgcn_mfma_f32_16x16x32_bf16(
                a, bfrag, acc1[m], 0, 0, 0);
        }
#pragma unroll
        for (int m = 0; m < 2; ++m) {
#pragma unroll
            for (int r = 0; r < 4; ++r) {
                const int row = m * 16 + lh * 4 + r;
                const int c   = wv * 16 + lr;
                const float v = acc1[m][r];               // bias folded in
                const float s = v / (1.0f + __expf(-v));
                const int byte = row * 256 + (((c << 1)) ^ ((row & 7) << 4));
                h1_s[byte >> 1] = f2b(s);
            }
        }
    }
    __syncthreads();

    // ---- filter layer 2 via MFMA: [32,128] @ [128,384] -> f_pack ----
    {
        floatx4 acc[2][3];
#pragma unroll
        for (int m = 0; m < 2; ++m)
#pragma unroll
            for (int n = 0; n < 3; ++n) acc[m][n] = (floatx4){0.f, 0.f, 0.f, 0.f};

#pragma unroll
        for (int kt = 0; kt < 4; ++kt) {
            const int kbyte = kt * 64 + lh * 16;
            const int r0 = lr, r1 = 16 + lr;
            const int b0 = r0 * 256 + (kbyte ^ ((r0 & 7) << 4));
            const int bb1 = r1 * 256 + (kbyte ^ ((r1 & 7) << 4));
            const short8 a0 = *reinterpret_cast<const short8*>(&h1_s[b0 >> 1]);
            const short8 a1 = *reinterpret_cast<const short8*>(&h1_s[bb1 >> 1]);
#pragma unroll
            for (int n = 0; n < 3; ++n) {
                const int tile = wv * 3 + n;
                const short8 b = *reinterpret_cast<const short8*>(
                    &Wf2b[(((kt * 24) + tile) * 64 + lane) * 8]);
                acc[0][n] = __builtin_amdgcn_mfma_f32_16x16x32_bf16(
                    a0, b, acc[0][n], 0, 0, 0);
                acc[1][n] = __builtin_amdgcn_mfma_f32_16x16x32_bf16(
                    a1, b, acc[1][n], 0, 0, 0);
            }
        }

#pragma unroll
        for (int n = 0; n < 3; ++n) {
            const int c  = (wv * 3 + n) * 16 + lr;
            const int cc = c & 127, p = c >> 7;
            const float bb = bf2[c];
#pragma unroll
            for (int m = 0; m < 2; ++m) {
#pragma unroll
                for (int r = 0; r < 4; ++r) {
                    const int row = m * 16 + lh * 4 + r;
                    f_pack[row * FP_STRIDE + cc * 4 + p] =
                        f2b((acc[m][n][r] + bb) * cut_s[row]);
                }
            }
        }
    }
    __syncthreads();

    // ---- message phase: 8-deep prefetch then compute ----
    {
        const int c   = t & 127;
        const int sub = t >> 7;
        const ushort8v* sp8 = (const ushort8v*)src_pack;

        ushort8v sp[8];
        ushort4  fpv[8];
#pragma unroll
        for (int k = 0; k < 8; ++k) {
            const int i = sub * 8 + k;
            sp[k]  = sp8[(size_t)src_s[i] * 128 + c];
            fpv[k] = *reinterpret_cast<const ushort4*>(
                &f_pack[i * FP_STRIDE + c * 4]);
        }

        float aq = 0.f, a0 = 0.f, a1 = 0.f, a2 = 0.f;
        int cur = tgt_s[sub * 8];
#pragma unroll
        for (int k = 0; k < 8; ++k) {
            const int i = sub * 8 + k;
            const int tg = tgt_s[i];
            if (tg != cur) {                    // subtile-uniform branch
                atomicAdd(&out_q[cur * HIDDEN + c], aq);
                atomicAdd(&out_mu[(cur * 3 + 0) * HIDDEN + c], a0);
                atomicAdd(&out_mu[(cur * 3 + 1) * HIDDEN + c], a1);
                atomicAdd(&out_mu[(cur * 3 + 2) * HIDDEN + c], a2);
                aq = a0 = a1 = a2 = 0.f;
                cur = tg;
            }
            const float xrr = b2f(sp[k][1]) * b2f(fpv[k].y);
            const float xmm = b2f(sp[k][2]) * b2f(fpv[k].z);
            aq = fmaf(b2f(sp[k][0]), b2f(fpv[k].x), aq);
            a0 = fmaf(uv_s[i][0], xrr, fmaf(b2f(sp[k][4]), xmm, a0));
            a1 = fmaf(uv_s[i][1], xrr, fmaf(b2f(sp[k][5]), xmm, a1));
            a2 = fmaf(uv_s[i][2], xrr, fmaf(b2f(sp[k][6]), xmm, a2));
        }
        atomicAdd(&out_q[cur * HIDDEN + c], aq);
        atomicAdd(&out_mu[(cur * 3 + 0) * HIDDEN + c], a0);
        atomicAdd(&out_mu[(cur * 3 + 1) * HIDDEN + c], a1);
        atomicAdd(&out_mu[(cur * 3 + 2) * HIDDEN + c], a2);
    }
}

// ---------------------------------------------------------------------------
extern "C" void kernel_launch(void* const* d_in, const int* in_sizes, int n_in,
                              void* d_out, int out_size, void* d_ws, size_t ws_size,
                              hipStream_t stream) {
    const float* q   = (const float*)d_in[0];
    const float* mu  = (const float*)d_in[1];
    const int*   ei  = (const int*)  d_in[2];
    const float* rbf = (const float*)d_in[3];
    const float* uv  = (const float*)d_in[4];
    const float* cut = (const float*)d_in[5];
    const float* W1  = (const float*)d_in[6];
    const float* b1  = (const float*)d_in[7];
    const float* W2  = (const float*)d_in[8];
    const float* b2  = (const float*)d_in[9];
    const float* Wf1 = (const float*)d_in[10];
    const float* bf1 = (const float*)d_in[11];
    const float* Wf2 = (const float*)d_in[12];
    const float* bf2 = (const float*)d_in[13];

    float* out    = (float*)d_out;
    float* out_q  = out;
    float* out_mu = out + N_NODES * HIDDEN;

    // ws layout (bytes), total ~22.3 MB
    char* ws = (char*)d_ws;
    size_t off = 0;
    ushort* Wf2b     = (ushort*)(ws + off); off += 98304;
    ushort* W1b      = (ushort*)(ws + off); off += 98304;
    ushort* W2b      = (ushort*)(ws + off); off += 294912;
    ushort* Wf1b     = (ushort*)(ws + off); off += 8192;
    ushort* src_pack = (ushort*)(ws + off); off += (size_t)N_NODES * 128 * 8 * 2;
    int*    perm     = (int*)   (ws + off); off += (size_t)N_EDGES * 4;
    int*    counts   = (int*)   (ws + off); off += (size_t)N_NODES * 4 + 960;
    int*    cursor   = (int*)   (ws + off); off += (size_t)N_NODES * 4 + 960;
    const bool ws_ok = (off <= ws_size);   // constant across calls

    if (ws_ok)
        hipMemsetAsync(counts, 0, (size_t)N_NODES * 4, stream);

    // A: fused prep (+ histogram)
    prep_kernel<<<A_Q + A_MU + A_PK + A_W + A_H, 256, 0, stream>>>(
        (const float4*)q, (const float4*)mu, mu, Wf2, W1, W2, Wf1, bf1, ei,
        (float4*)d_out, (ushort4*)src_pack, Wf2b, W1b, W2b, Wf1b,
        counts, ws_ok ? 1 : 0);

    if (ws_ok) {
        scan_kernel<<<1, SCAN_NT, 0, stream>>>(counts, cursor);
    } else {
        iota_kernel<<<(N_EDGES + 255) / 256, 256, 0, stream>>>(perm);
    }

    // D: node MLP (+ scatter when sorting)
    node_scatter_kernel<<<ws_ok ? (D_NODE + D_SCAT) : D_NODE, 512, 0, stream>>>(
        q, W1b, b1, W2b, b2, ei, cursor, perm, src_pack);

    edge_kernel<<<N_EDGES / 32, 512, 0, stream>>>(
        src_pack, ei, perm, rbf, uv, cut, Wf1b, Wf2b, bf2, out_q, out_mu);
}